// Round 2
// baseline (806.049 us; speedup 1.0000x reference)
//
#include <hip/hip_runtime.h>
#include <stdint.h>

typedef unsigned short u16;
using s16x8 = __attribute__((ext_vector_type(8))) short;
using f32x4 = __attribute__((ext_vector_type(4))) float;
using u16x8 = __attribute__((ext_vector_type(8))) unsigned short;
using u16x4 = __attribute__((ext_vector_type(4))) unsigned short;

#define DEVINL __device__ __forceinline__

DEVINL float b2f(u16 u) { return __uint_as_float(((uint32_t)u) << 16); }
DEVINL u16 f2b(float f) {
  uint32_t x = __float_as_uint(f);
  return (u16)((x + 0x7fffu + ((x >> 16) & 1u)) >> 16);
}
// dtype-agnostic load/store: isbf=1 -> bf16 (u16), else fp32
DEVINL float ldf(const void* p, size_t i, int isbf) {
  return isbf ? b2f(((const u16*)p)[i]) : ((const float*)p)[i];
}
DEVINL void stf(void* p, size_t i, int isbf, float v) {
  if (isbf) ((u16*)p)[i] = f2b(v);
  else      ((float*)p)[i] = v;
}

constexpr int NN = 10000;     // nodes
constexpr int NE = 80000;     // edges (no self loops)
constexpr int NTOT = 90000;   // edges + self loops

// ---------------------------------------------------------------- dtype detect
// bf16 N(0,1) data: every u16's exponent field lies in a narrow band.
// fp32 data read as u16: even words are uniform mantissa bits (~23% in band).
__global__ void detect_kernel(const void* __restrict__ x, int* __restrict__ flag) {
  int lane = threadIdx.x;  // 64
  u16 w = ((const u16*)x)[lane * 97 + 13];
  int e = (w >> 7) & 0xFF;
  int sane = (e >= 0x50 && e <= 0x8A) ? 1 : 0;
  unsigned long long b = __ballot(sane);
  if (lane == 0) flag[0] = (__popcll(b) >= 56) ? 1 : 0;
}

// canonicalize x -> bf16
__global__ void cvt_kernel(const void* __restrict__ in, u16* __restrict__ out,
                           int n, const int* __restrict__ FLAG) {
  int isbf = *FLAG;
  int i = blockIdx.x * 256 + threadIdx.x;
  if (i >= n) return;
  out[i] = isbf ? ((const u16*)in)[i] : f2b(((const float*)in)[i]);
}

// ---------------------------------------------------------------- transpose
// out[c*R + r] = in[r*C + c]   (always emits bf16)
__global__ void transpose_kernel(const void* __restrict__ in, u16* __restrict__ out,
                                 int R, int C, const int* __restrict__ FLAG) {
  int isbf = *FLAG;
  __shared__ float tile[32][33];
  int bx = blockIdx.x * 32, by = blockIdx.y * 32;
  int tx = threadIdx.x, ty = threadIdx.y;  // (32,8)
  for (int j = 0; j < 32; j += 8) {
    int r = by + ty + j, c = bx + tx;
    if (r < R && c < C) tile[ty + j][tx] = ldf(in, (size_t)r * C + c, isbf);
  }
  __syncthreads();
  for (int j = 0; j < 32; j += 8) {
    int r = bx + ty + j, c = by + tx;
    if (r < C && c < R) out[(size_t)r * R + c] = f2b(tile[tx][ty + j]);
  }
}

// ---------------------------------------------------------------- CSR build
__global__ void init_deg_kernel(int* __restrict__ deg) {
  int i = blockIdx.x * blockDim.x + threadIdx.x;
  if (i < NN) deg[i] = 1;  // self loop
}

__global__ void count_deg_kernel(const int* __restrict__ ei, int* __restrict__ deg) {
  int e = blockIdx.x * blockDim.x + threadIdx.x;
  if (e < NE) atomicAdd(&deg[ei[NE + e]], 1);
}

__global__ __launch_bounds__(1024) void scan_kernel(const int* __restrict__ deg,
                                                    int* __restrict__ offs,
                                                    int* __restrict__ cursor, int n) {
  __shared__ int buf[1024];
  __shared__ int carry;
  int tid = threadIdx.x;
  if (tid == 0) carry = 0;
  __syncthreads();
  for (int base = 0; base < n; base += 1024) {
    int idx = base + tid;
    int v = (idx < n) ? deg[idx] : 0;
    buf[tid] = v;
    __syncthreads();
    for (int off = 1; off < 1024; off <<= 1) {
      int add = (tid >= off) ? buf[tid - off] : 0;
      __syncthreads();
      buf[tid] += add;
      __syncthreads();
    }
    int inc = buf[tid] + carry;
    if (idx < n) { offs[idx + 1] = inc; cursor[idx] = inc - v; }
    __syncthreads();
    if (tid == 0) carry += buf[1023];
    __syncthreads();
  }
  if (tid == 0) offs[0] = 0;
}

__global__ void scatter_kernel(const int* __restrict__ ei, int* __restrict__ cursor,
                               int* __restrict__ csr_src) {
  int e = blockIdx.x * blockDim.x + threadIdx.x;
  if (e >= NTOT) return;
  int s, d;
  if (e < NE) { s = ei[e]; d = ei[NE + e]; }
  else        { s = e - NE; d = s; }
  int pos = atomicAdd(&cursor[d], 1);
  csr_src[pos] = s;
}

// ---------------------------------------------------------------- GEMM (bf16 MFMA)
// C[M,N] = A[M,K] * B[K,N], with B given TRANSPOSED as Bt[N,K] row-major.
template <int BM, int BN, int WM, int WN>
__global__ __launch_bounds__(256) void gemm_kernel(const u16* __restrict__ A,
                                                   const u16* __restrict__ Bt,
                                                   u16* __restrict__ C,
                                                   int M, int K, int N) {
  constexpr int BK = 64;             // 128 bytes per LDS row
  constexpr int WTM = BM / WM, WTN = BN / WN;
  constexpr int FM = WTM / 16, FN = WTN / 16;
  constexpr int ACH = BM * 8 / 256;
  constexpr int BCH = BN * 8 / 256;

  __shared__ u16 lA[BM * BK];
  __shared__ u16 lB[BN * BK];

  int tid = threadIdx.x;
  int lane = tid & 63, wid = tid >> 6;
  int wm = wid / WN, wn = wid % WN;
  int bm0 = blockIdx.x * BM, bn0 = blockIdx.y * BN;

  f32x4 acc[FM][FN];
#pragma unroll
  for (int m = 0; m < FM; m++)
#pragma unroll
    for (int n = 0; n < FN; n++) acc[m][n] = (f32x4){0.f, 0.f, 0.f, 0.f};

  for (int k0 = 0; k0 < K; k0 += BK) {
    int4 ra[ACH], rb[BCH];
#pragma unroll
    for (int ii = 0; ii < ACH; ii++) {
      int ch = ii * 256 + tid;
      int row = ch >> 3;
      int colb = ((ch & 7) ^ (row & 7)) << 4;
      int grow = bm0 + row;
      if (grow > M - 1) grow = M - 1;
      ra[ii] = *(const int4*)((const char*)A + ((size_t)grow * K + k0) * 2 + colb);
    }
#pragma unroll
    for (int ii = 0; ii < BCH; ii++) {
      int ch = ii * 256 + tid;
      int row = ch >> 3;
      int colb = ((ch & 7) ^ (row & 7)) << 4;
      int grow = bn0 + row;  // N multiple of BN for all layers
      rb[ii] = *(const int4*)((const char*)Bt + ((size_t)grow * K + k0) * 2 + colb);
    }
    __syncthreads();
#pragma unroll
    for (int ii = 0; ii < ACH; ii++) *(int4*)((char*)lA + (ii * 256 + tid) * 16) = ra[ii];
#pragma unroll
    for (int ii = 0; ii < BCH; ii++) *(int4*)((char*)lB + (ii * 256 + tid) * 16) = rb[ii];
    __syncthreads();

    int swz = (lane & 7) << 4;
#pragma unroll
    for (int ks = 0; ks < 2; ks++) {
      int kcolb = ks * 64 + ((lane >> 4) << 4);
      s16x8 af[FM], bf[FN];
#pragma unroll
      for (int m = 0; m < FM; m++) {
        int row = wm * WTM + m * 16 + (lane & 15);
        af[m] = *(const s16x8*)((const char*)lA + row * 128 + (kcolb ^ swz));
      }
#pragma unroll
      for (int n = 0; n < FN; n++) {
        int row = wn * WTN + n * 16 + (lane & 15);
        bf[n] = *(const s16x8*)((const char*)lB + row * 128 + (kcolb ^ swz));
      }
#pragma unroll
      for (int m = 0; m < FM; m++)
#pragma unroll
        for (int n = 0; n < FN; n++)
          acc[m][n] = __builtin_amdgcn_mfma_f32_16x16x32_bf16(af[m], bf[n], acc[m][n], 0, 0, 0);
    }
    __syncthreads();
  }

  int r0 = (lane >> 4) * 4;
#pragma unroll
  for (int m = 0; m < FM; m++) {
#pragma unroll
    for (int n = 0; n < FN; n++) {
#pragma unroll
      for (int r = 0; r < 4; r++) {
        int grow = bm0 + wm * WTM + m * 16 + r0 + r;
        int gcol = bn0 + wn * WTN + n * 16 + (lane & 15);
        if (grow < M) C[(size_t)grow * N + gcol] = f2b(acc[m][n][r]);
      }
    }
  }
}

// ---------------------------------------------------------------- hs/hd dots
__global__ __launch_bounds__(256) void dot_av_kernel(const u16* __restrict__ h,
                                                     const void* __restrict__ asrc,
                                                     const void* __restrict__ adst,
                                                     float* __restrict__ hs,
                                                     float* __restrict__ hd,
                                                     int H, int C, int n,
                                                     const int* __restrict__ FLAG) {
  int isbf = *FLAG;
  int wid = threadIdx.x >> 6, lane = threadIdx.x & 63;
  int pair = blockIdx.x * 4 + wid;
  if (pair >= n * H) return;
  int node = pair / H, head = pair % H;
  const u16* hp = h + (size_t)node * H * C + head * C;
  float s = 0.f, d = 0.f;
  for (int c = lane; c < C; c += 64) {
    float v = b2f(hp[c]);
    s += v * ldf(asrc, (size_t)head * C + c, isbf);
    d += v * ldf(adst, (size_t)head * C + c, isbf);
  }
  for (int o = 32; o; o >>= 1) { s += __shfl_down(s, o); d += __shfl_down(d, o); }
  if (lane == 0) { hs[pair] = s; hd[pair] = d; }
}

// ---------------------------------------------------------------- edge softmax
__global__ void softmax_kernel(const int* __restrict__ csr_src, const int* __restrict__ offs,
                               const float* __restrict__ hs, const float* __restrict__ hd,
                               float* __restrict__ alpha, int H, int n) {
  int idx = blockIdx.x * blockDim.x + threadIdx.x;
  if (idx >= n * H) return;
  int i = idx / H, hh = idx % H;
  float hdv = hd[idx];
  int p0 = offs[i], p1 = offs[i + 1];
  float m = -1e30f;
  for (int p = p0; p < p1; ++p) {
    float e = hs[csr_src[p] * H + hh] + hdv;
    e = e > 0.f ? e : 0.2f * e;
    m = fmaxf(m, e);
  }
  float den = 0.f;
  for (int p = p0; p < p1; ++p) {
    float e = hs[csr_src[p] * H + hh] + hdv;
    e = e > 0.f ? e : 0.2f * e;
    float pe = __expf(e - m);
    alpha[(size_t)p * H + hh] = pe;
    den += pe;
  }
  float inv = 1.f / (den + 1e-16f);
  for (int p = p0; p < p1; ++p) alpha[(size_t)p * H + hh] *= inv;
}

// ---------------------------------------------------------------- aggregation
// outb != null: write bf16 ws buffer (layers 1,2). outb == null: write d_out
// (dtype per FLAG) at offset 10000 plus fp32 aux (layer 3).
template <int HC, int VPT, int TPB>
__global__ __launch_bounds__(TPB) void aggregate_kernel(
    const u16* __restrict__ h, const float* __restrict__ alpha,
    const int* __restrict__ csr_src, const int* __restrict__ offs,
    const void* __restrict__ bias, u16* __restrict__ outb, void* __restrict__ outv,
    float* __restrict__ auxf, int H, int C, int do_elu, const int* __restrict__ FLAG) {
  int isbf = *FLAG;
  int i = blockIdx.x;
  int t = threadIdx.x;
  int c0 = t * VPT;
  int head = c0 / C;
  float acc[VPT];
#pragma unroll
  for (int j = 0; j < VPT; j++) acc[j] = 0.f;
  int p0 = offs[i], p1 = offs[i + 1];
  for (int p = p0; p < p1; ++p) {
    int s = csr_src[p];
    float al = alpha[(size_t)p * H + head];
    const u16* hp = h + (size_t)s * HC + c0;
    if constexpr (VPT == 8) {
      u16x8 v = *(const u16x8*)hp;
#pragma unroll
      for (int j = 0; j < 8; j++) acc[j] += al * b2f(v[j]);
    } else if constexpr (VPT == 4) {
      u16x4 v = *(const u16x4*)hp;
#pragma unroll
      for (int j = 0; j < 4; j++) acc[j] += al * b2f(v[j]);
    } else {
      acc[0] += al * b2f(hp[0]);
    }
  }
  float r[VPT];
#pragma unroll
  for (int j = 0; j < VPT; j++) {
    r[j] = acc[j] + ldf(bias, c0 + j, isbf);
    if (do_elu) r[j] = r[j] > 0.f ? r[j] : expm1f(r[j]);
  }
  if (outb) {
    if constexpr (VPT == 8) {
      u16x8 o;
#pragma unroll
      for (int j = 0; j < 8; j++) o[j] = f2b(r[j]);
      *(u16x8*)(outb + (size_t)i * HC + c0) = o;
    } else if constexpr (VPT == 4) {
      u16x4 o;
#pragma unroll
      for (int j = 0; j < 4; j++) o[j] = f2b(r[j]);
      *(u16x4*)(outb + (size_t)i * HC + c0) = o;
    } else {
      outb[(size_t)i * HC + c0] = f2b(r[0]);
    }
  } else {
#pragma unroll
    for (int j = 0; j < VPT; j++) {
      if (auxf) auxf[(size_t)i * HC + c0 + j] = r[j];
      stf(outv, (size_t)10000 + (size_t)i * HC + c0 + j, isbf, r[j]);
    }
  }
}

// ---------------------------------------------------------------- MLP head
__global__ __launch_bounds__(256) void mlp_kernel(const float* __restrict__ x3f,
                                                  const void* __restrict__ r1w,
                                                  const void* __restrict__ r1b,
                                                  const void* __restrict__ r2w,
                                                  const void* __restrict__ r2b,
                                                  const void* __restrict__ r3w,
                                                  const void* __restrict__ r3b,
                                                  void* __restrict__ scores,
                                                  const int* __restrict__ FLAG) {
  int isbf = *FLAG;
  __shared__ float sx[64], t1[256], t2[128];
  int i = blockIdx.x, t = threadIdx.x;
  if (t < 64) sx[t] = x3f[(size_t)i * 64 + t];
  __syncthreads();
  float a = 0.f;
  for (int k = 0; k < 64; k++) a += sx[k] * ldf(r1w, (size_t)k * 256 + t, isbf);
  a += ldf(r1b, t, isbf);
  t1[t] = fmaxf(a, 0.f);
  __syncthreads();
  if (t < 128) {
    float b = 0.f;
    for (int k = 0; k < 256; k++) b += t1[k] * ldf(r2w, (size_t)k * 128 + t, isbf);
    b += ldf(r2b, t, isbf);
    t2[t] = fmaxf(b, 0.f);
  }
  __syncthreads();
  if (t < 64) {
    float v = t2[t] * ldf(r3w, t, isbf) + t2[t + 64] * ldf(r3w, t + 64, isbf);
    for (int o = 32; o; o >>= 1) v += __shfl_down(v, o);
    if (t == 0) stf(scores, i, isbf, v + ldf(r3b, 0, isbf));
  }
}

// ---------------------------------------------------------------- launch
extern "C" void kernel_launch(void* const* d_in, const int* in_sizes, int n_in,
                              void* d_out, int out_size, void* d_ws, size_t ws_size,
                              hipStream_t stream) {
  const void* x   = d_in[0];
  const int* ei   = (const int*)d_in[1];
  const void* W1  = d_in[2];
  const void* as1 = d_in[3];
  const void* ad1 = d_in[4];
  const void* b1  = d_in[5];
  const void* W2  = d_in[6];
  const void* as2 = d_in[7];
  const void* ad2 = d_in[8];
  const void* b2  = d_in[9];
  const void* W3  = d_in[10];
  const void* as3 = d_in[11];
  const void* ad3 = d_in[12];
  const void* b3  = d_in[13];
  const void* r1w = d_in[14];
  const void* r1b = d_in[15];
  const void* r2w = d_in[16];
  const void* r2b = d_in[17];
  const void* r3w = d_in[18];
  const void* r3b = d_in[19];

  char* ws = (char*)d_ws;
  size_t o = 0;
  auto alloc = [&](size_t bytes) { void* p = ws + o; o += (bytes + 255) & ~(size_t)255; return p; };
  u16* XC     = (u16*)alloc((size_t)NN * 768 * 2);
  u16* W1T    = (u16*)alloc((size_t)2048 * 768 * 2);
  u16* W2T    = (u16*)alloc((size_t)1024 * 2048 * 2);
  u16* W3T    = (u16*)alloc((size_t)64 * 1024 * 2);
  u16* Hbuf   = (u16*)alloc((size_t)NN * 2048 * 2);
  u16* Xbuf   = (u16*)alloc((size_t)NN * 2048 * 2);
  float* X3F  = (float*)alloc((size_t)NN * 64 * 4);
  float* HS   = (float*)alloc((size_t)NN * 8 * 4);
  float* HD   = (float*)alloc((size_t)NN * 8 * 4);
  int* DEG    = (int*)alloc((size_t)NN * 4);
  int* OFFS   = (int*)alloc((size_t)(NN + 1) * 4);
  int* CURSOR = (int*)alloc((size_t)NN * 4);
  int* CSR    = (int*)alloc((size_t)NTOT * 4);
  float* ALPHA = (float*)alloc((size_t)NTOT * 8 * 4);
  int* FLAG   = (int*)alloc(256);

  detect_kernel<<<1, 64, 0, stream>>>(x, FLAG);
  cvt_kernel<<<(NN * 768 + 255) / 256, 256, 0, stream>>>(x, XC, NN * 768, FLAG);

  transpose_kernel<<<dim3(2048 / 32, 768 / 32), dim3(32, 8), 0, stream>>>(W1, W1T, 768, 2048, FLAG);
  transpose_kernel<<<dim3(1024 / 32, 2048 / 32), dim3(32, 8), 0, stream>>>(W2, W2T, 2048, 1024, FLAG);
  transpose_kernel<<<dim3(64 / 32, 1024 / 32), dim3(32, 8), 0, stream>>>(W3, W3T, 1024, 64, FLAG);

  init_deg_kernel<<<(NN + 255) / 256, 256, 0, stream>>>(DEG);
  count_deg_kernel<<<(NE + 255) / 256, 256, 0, stream>>>(ei, DEG);
  scan_kernel<<<1, 1024, 0, stream>>>(DEG, OFFS, CURSOR, NN);
  scatter_kernel<<<(NTOT + 255) / 256, 256, 0, stream>>>(ei, CURSOR, CSR);

  const int MT = (NN + 127) / 128;  // 79

  // ---- layer 1: 768 -> 8 x 256
  gemm_kernel<128, 128, 2, 2><<<dim3(MT, 2048 / 128), 256, 0, stream>>>(XC, W1T, Hbuf, NN, 768, 2048);
  dot_av_kernel<<<(NN * 8 + 3) / 4, 256, 0, stream>>>(Hbuf, as1, ad1, HS, HD, 8, 256, NN, FLAG);
  softmax_kernel<<<(NN * 8 + 255) / 256, 256, 0, stream>>>(CSR, OFFS, HS, HD, ALPHA, 8, NN);
  aggregate_kernel<2048, 8, 256><<<NN, 256, 0, stream>>>(Hbuf, ALPHA, CSR, OFFS, b1, Xbuf, nullptr, nullptr, 8, 256, 1, FLAG);

  // ---- layer 2: 2048 -> 4 x 256
  gemm_kernel<128, 128, 2, 2><<<dim3(MT, 1024 / 128), 256, 0, stream>>>(Xbuf, W2T, Hbuf, NN, 2048, 1024);
  dot_av_kernel<<<(NN * 4 + 3) / 4, 256, 0, stream>>>(Hbuf, as2, ad2, HS, HD, 4, 256, NN, FLAG);
  softmax_kernel<<<(NN * 4 + 255) / 256, 256, 0, stream>>>(CSR, OFFS, HS, HD, ALPHA, 4, NN);
  aggregate_kernel<1024, 4, 256><<<NN, 256, 0, stream>>>(Hbuf, ALPHA, CSR, OFFS, b2, Xbuf, nullptr, nullptr, 4, 256, 1, FLAG);

  // ---- layer 3: 1024 -> 1 x 64
  gemm_kernel<128, 64, 4, 1><<<dim3(MT, 1), 256, 0, stream>>>(Xbuf, W3T, Hbuf, NN, 1024, 64);
  dot_av_kernel<<<(NN + 3) / 4, 256, 0, stream>>>(Hbuf, as3, ad3, HS, HD, 1, 64, NN, FLAG);
  softmax_kernel<<<(NN + 255) / 256, 256, 0, stream>>>(CSR, OFFS, HS, HD, ALPHA, 1, NN);
  aggregate_kernel<64, 1, 64><<<NN, 64, 0, stream>>>(Hbuf, ALPHA, CSR, OFFS, b3, nullptr, d_out, X3F, 1, 64, 0, FLAG);

  // ---- reasoning MLP
  mlp_kernel<<<NN, 256, 0, stream>>>(X3F, r1w, r1b, r2w, r2b, r3w, r3b, d_out, FLAG);
}

// Round 3
// 562.102 us; speedup vs baseline: 1.4340x; 1.4340x over previous
//
#include <hip/hip_runtime.h>
#include <stdint.h>

typedef unsigned short u16;
using s16x8 = __attribute__((ext_vector_type(8))) short;
using f32x4 = __attribute__((ext_vector_type(4))) float;
using u16x8 = __attribute__((ext_vector_type(8))) unsigned short;
using u16x4 = __attribute__((ext_vector_type(4))) unsigned short;

#define DEVINL __device__ __forceinline__

DEVINL float b2f(u16 u) { return __uint_as_float(((uint32_t)u) << 16); }
DEVINL u16 f2b(float f) {
  uint32_t x = __float_as_uint(f);
  return (u16)((x + 0x7fffu + ((x >> 16) & 1u)) >> 16);
}
// dtype-agnostic load/store: isbf=1 -> bf16 (u16), else fp32
DEVINL float ldf(const void* p, size_t i, int isbf) {
  return isbf ? b2f(((const u16*)p)[i]) : ((const float*)p)[i];
}
DEVINL void stf(void* p, size_t i, int isbf, float v) {
  if (isbf) ((u16*)p)[i] = f2b(v);
  else      ((float*)p)[i] = v;
}

typedef __attribute__((address_space(1))) const void gvoid;
typedef __attribute__((address_space(3))) void lvoid;
DEVINL void gload_lds16(const u16* g, u16* l) {
  __builtin_amdgcn_global_load_lds((gvoid*)g, (lvoid*)l, 16, 0, 0);
}

constexpr int NN = 10000;     // nodes
constexpr int NE = 80000;     // edges (no self loops)
constexpr int NTOT = 90000;   // edges + self loops

// ---------------------------------------------------------------- dtype detect
__global__ void detect_kernel(const void* __restrict__ x, int* __restrict__ flag) {
  int lane = threadIdx.x;  // 64
  u16 w = ((const u16*)x)[lane * 97 + 13];
  int e = (w >> 7) & 0xFF;
  int sane = (e >= 0x50 && e <= 0x8A) ? 1 : 0;
  unsigned long long b = __ballot(sane);
  if (lane == 0) flag[0] = (__popcll(b) >= 56) ? 1 : 0;
}

// canonicalize x -> bf16
__global__ void cvt_kernel(const void* __restrict__ in, u16* __restrict__ out,
                           int n, const int* __restrict__ FLAG) {
  int isbf = *FLAG;
  int i = blockIdx.x * 256 + threadIdx.x;
  if (i >= n) return;
  out[i] = isbf ? ((const u16*)in)[i] : f2b(((const float*)in)[i]);
}

// ---------------------------------------------------------------- transpose
__global__ void transpose_kernel(const void* __restrict__ in, u16* __restrict__ out,
                                 int R, int C, const int* __restrict__ FLAG) {
  int isbf = *FLAG;
  __shared__ float tile[32][33];
  int bx = blockIdx.x * 32, by = blockIdx.y * 32;
  int tx = threadIdx.x, ty = threadIdx.y;  // (32,8)
  for (int j = 0; j < 32; j += 8) {
    int r = by + ty + j, c = bx + tx;
    if (r < R && c < C) tile[ty + j][tx] = ldf(in, (size_t)r * C + c, isbf);
  }
  __syncthreads();
  for (int j = 0; j < 32; j += 8) {
    int r = bx + ty + j, c = by + tx;
    if (r < C && c < R) out[(size_t)r * R + c] = f2b(tile[tx][ty + j]);
  }
}

// ---------------------------------------------------------------- CSR build
__global__ void init_deg_kernel(int* __restrict__ deg) {
  int i = blockIdx.x * blockDim.x + threadIdx.x;
  if (i < NN) deg[i] = 1;  // self loop
}

__global__ void count_deg_kernel(const int* __restrict__ ei, int* __restrict__ deg) {
  int e = blockIdx.x * blockDim.x + threadIdx.x;
  if (e < NE) atomicAdd(&deg[ei[NE + e]], 1);
}

__global__ __launch_bounds__(1024) void scan_kernel(const int* __restrict__ deg,
                                                    int* __restrict__ offs,
                                                    int* __restrict__ cursor, int n) {
  __shared__ int buf[1024];
  __shared__ int carry;
  int tid = threadIdx.x;
  if (tid == 0) carry = 0;
  __syncthreads();
  for (int base = 0; base < n; base += 1024) {
    int idx = base + tid;
    int v = (idx < n) ? deg[idx] : 0;
    buf[tid] = v;
    __syncthreads();
    for (int off = 1; off < 1024; off <<= 1) {
      int add = (tid >= off) ? buf[tid - off] : 0;
      __syncthreads();
      buf[tid] += add;
      __syncthreads();
    }
    int inc = buf[tid] + carry;
    if (idx < n) { offs[idx + 1] = inc; cursor[idx] = inc - v; }
    __syncthreads();
    if (tid == 0) carry += buf[1023];
    __syncthreads();
  }
  if (tid == 0) offs[0] = 0;
}

__global__ void scatter_kernel(const int* __restrict__ ei, int* __restrict__ cursor,
                               int* __restrict__ csr_src) {
  int e = blockIdx.x * blockDim.x + threadIdx.x;
  if (e >= NTOT) return;
  int s, d;
  if (e < NE) { s = ei[e]; d = ei[NE + e]; }
  else        { s = e - NE; d = s; }
  int pos = atomicAdd(&cursor[d], 1);
  csr_src[pos] = s;
}

// ---------------------------------------------------------------- GEMM (bf16 MFMA)
// C[M,N] = A[M,K] * Bt[N,K]^T. m97 structure: global_load_lds width-16 staging,
// linear LDS, 2 barriers/K-step, XCD-bijective block remap (N fastest in chunk),
// LDS-staged coalesced C store.
template <int BM, int BN, int WM, int WN>
__global__ __launch_bounds__(256) void gemm_kernel(const u16* __restrict__ A,
                                                   const u16* __restrict__ Bt,
                                                   u16* __restrict__ C,
                                                   int M, int K, int N, int nN) {
  constexpr int BK = 64;             // 128 B per LDS row
  constexpr int WTM = BM / WM, WTN = BN / WN;
  constexpr int FM = WTM / 16, FN = WTN / 16;
  constexpr int ACH = BM / 32;       // 1KB staging chunks per wave (A)
  constexpr int BCH = BN / 32;

  __shared__ u16 smem[(BM + BN) * BK];
  u16* lA = smem;
  u16* lB = smem + BM * BK;

  int tid = threadIdx.x;
  int lane = tid & 63, wid = tid >> 6;
  int wm = wid / WN, wn = wid % WN;

  // bijective XCD remap (m204): each XCD owns a contiguous wgid chunk;
  // wgid%nN is the N tile (fastest) -> B panel stays L2-resident per XCD.
  int nwg = gridDim.x;
  int q = nwg >> 3, r = nwg & 7;
  int xcd = blockIdx.x & 7, pos = blockIdx.x >> 3;
  int wgid = (xcd < r ? xcd * (q + 1) : r * (q + 1) + (xcd - r) * q) + pos;
  int bm0 = (wgid / nN) * BM, bn0 = (wgid % nN) * BN;

  int srow = lane >> 3;          // staging: row within 8-row chunk
  int scol = (lane & 7) * 8;     // staging: u16 col (16B granules)

  f32x4 acc[FM][FN];
#pragma unroll
  for (int m = 0; m < FM; m++)
#pragma unroll
    for (int n = 0; n < FN; n++) acc[m][n] = (f32x4){0.f, 0.f, 0.f, 0.f};

  for (int k0 = 0; k0 < K; k0 += BK) {
    // ---- stage tile via global_load_lds (linear LDS, wave-uniform dest)
#pragma unroll
    for (int i = 0; i < ACH; i++) {
      int c = wid * ACH + i;
      int row = c * 8 + srow;
      int grow = bm0 + row;
      if (grow > M - 1) grow = M - 1;
      gload_lds16(A + (size_t)grow * K + k0 + scol, lA + c * 512);
    }
#pragma unroll
    for (int i = 0; i < BCH; i++) {
      int c = wid * BCH + i;
      int row = c * 8 + srow;
      gload_lds16(Bt + (size_t)(bn0 + row) * K + k0 + scol, lB + c * 512);
    }
    __syncthreads();  // drains vmcnt(0) -> LDS tile ready

    // ---- MFMA over BK (2 x k=32 steps)
#pragma unroll
    for (int ks = 0; ks < 2; ks++) {
      int kb = ks * 64 + ((lane >> 4) << 4);  // byte offset within 128B row
      s16x8 af[FM], bf[FN];
#pragma unroll
      for (int m = 0; m < FM; m++) {
        int row = wm * WTM + m * 16 + (lane & 15);
        af[m] = *(const s16x8*)((const char*)lA + row * 128 + kb);
      }
#pragma unroll
      for (int n = 0; n < FN; n++) {
        int row = wn * WTN + n * 16 + (lane & 15);
        bf[n] = *(const s16x8*)((const char*)lB + row * 128 + kb);
      }
#pragma unroll
      for (int m = 0; m < FM; m++)
#pragma unroll
        for (int n = 0; n < FN; n++)
          acc[m][n] = __builtin_amdgcn_mfma_f32_16x16x32_bf16(af[m], bf[n], acc[m][n], 0, 0, 0);
    }
    __syncthreads();  // LDS consumed; safe to restage
  }

  // ---- epilogue: stage C tile in LDS (bf16), then coalesced 16B stores
  u16* lC = smem;  // BM*BN u16 <= (BM+BN)*BK for our configs
  int r0 = (lane >> 4) * 4;
#pragma unroll
  for (int m = 0; m < FM; m++)
#pragma unroll
    for (int n = 0; n < FN; n++)
#pragma unroll
      for (int rr = 0; rr < 4; rr++) {
        int row = wm * WTM + m * 16 + r0 + rr;
        int col = wn * WTN + n * 16 + (lane & 15);
        lC[row * BN + col] = f2b(acc[m][n][rr]);
      }
  __syncthreads();
  constexpr int CHUNKS = BM * BN / 2048;  // 16B chunks per thread
  constexpr int CPR = BN / 8;             // chunks per C row
#pragma unroll
  for (int j = 0; j < CHUNKS; j++) {
    int idx = j * 256 + tid;
    int row = idx / CPR, colb = (idx % CPR) * 16;
    int grow = bm0 + row;
    if (grow < M) {
      int4 v = *(const int4*)((const char*)lC + idx * 16);
      *(int4*)((char*)C + ((size_t)grow * N + bn0) * 2 + colb) = v;
    }
  }
}

// ---------------------------------------------------------------- hs/hd dots
__global__ __launch_bounds__(256) void dot_av_kernel(const u16* __restrict__ h,
                                                     const void* __restrict__ asrc,
                                                     const void* __restrict__ adst,
                                                     float* __restrict__ hs,
                                                     float* __restrict__ hd,
                                                     int H, int C, int n,
                                                     const int* __restrict__ FLAG) {
  int isbf = *FLAG;
  int wid = threadIdx.x >> 6, lane = threadIdx.x & 63;
  int pair = blockIdx.x * 4 + wid;
  if (pair >= n * H) return;
  int node = pair / H, head = pair % H;
  const u16* hp = h + (size_t)node * H * C + head * C;
  float s = 0.f, d = 0.f;
  for (int c = lane; c < C; c += 64) {
    float v = b2f(hp[c]);
    s += v * ldf(asrc, (size_t)head * C + c, isbf);
    d += v * ldf(adst, (size_t)head * C + c, isbf);
  }
  for (int o = 32; o; o >>= 1) { s += __shfl_down(s, o); d += __shfl_down(d, o); }
  if (lane == 0) { hs[pair] = s; hd[pair] = d; }
}

// ---------------------------------------------------------------- edge softmax
__global__ void softmax_kernel(const int* __restrict__ csr_src, const int* __restrict__ offs,
                               const float* __restrict__ hs, const float* __restrict__ hd,
                               float* __restrict__ alpha, int H, int n) {
  int idx = blockIdx.x * blockDim.x + threadIdx.x;
  if (idx >= n * H) return;
  int i = idx / H, hh = idx % H;
  float hdv = hd[idx];
  int p0 = offs[i], p1 = offs[i + 1];
  float m = -1e30f;
  for (int p = p0; p < p1; ++p) {
    float e = hs[csr_src[p] * H + hh] + hdv;
    e = e > 0.f ? e : 0.2f * e;
    m = fmaxf(m, e);
  }
  float den = 0.f;
  for (int p = p0; p < p1; ++p) {
    float e = hs[csr_src[p] * H + hh] + hdv;
    e = e > 0.f ? e : 0.2f * e;
    float pe = __expf(e - m);
    alpha[(size_t)p * H + hh] = pe;
    den += pe;
  }
  float inv = 1.f / (den + 1e-16f);
  for (int p = p0; p < p1; ++p) alpha[(size_t)p * H + hh] *= inv;
}

// ---------------------------------------------------------------- aggregation
template <int HC, int VPT, int TPB>
__global__ __launch_bounds__(TPB) void aggregate_kernel(
    const u16* __restrict__ h, const float* __restrict__ alpha,
    const int* __restrict__ csr_src, const int* __restrict__ offs,
    const void* __restrict__ bias, u16* __restrict__ outb, void* __restrict__ outv,
    float* __restrict__ auxf, int H, int C, int do_elu, const int* __restrict__ FLAG) {
  int isbf = *FLAG;
  int i = blockIdx.x;
  int t = threadIdx.x;
  int c0 = t * VPT;
  int head = c0 / C;
  float acc[VPT];
#pragma unroll
  for (int j = 0; j < VPT; j++) acc[j] = 0.f;
  int p0 = offs[i], p1 = offs[i + 1];
  for (int p = p0; p < p1; ++p) {
    int s = csr_src[p];
    float al = alpha[(size_t)p * H + head];
    const u16* hp = h + (size_t)s * HC + c0;
    if constexpr (VPT == 8) {
      u16x8 v = *(const u16x8*)hp;
#pragma unroll
      for (int j = 0; j < 8; j++) acc[j] += al * b2f(v[j]);
    } else if constexpr (VPT == 4) {
      u16x4 v = *(const u16x4*)hp;
#pragma unroll
      for (int j = 0; j < 4; j++) acc[j] += al * b2f(v[j]);
    } else {
      acc[0] += al * b2f(hp[0]);
    }
  }
  float r[VPT];
#pragma unroll
  for (int j = 0; j < VPT; j++) {
    r[j] = acc[j] + ldf(bias, c0 + j, isbf);
    if (do_elu) r[j] = r[j] > 0.f ? r[j] : expm1f(r[j]);
  }
  if (outb) {
    if constexpr (VPT == 8) {
      u16x8 o;
#pragma unroll
      for (int j = 0; j < 8; j++) o[j] = f2b(r[j]);
      *(u16x8*)(outb + (size_t)i * HC + c0) = o;
    } else if constexpr (VPT == 4) {
      u16x4 o;
#pragma unroll
      for (int j = 0; j < 4; j++) o[j] = f2b(r[j]);
      *(u16x4*)(outb + (size_t)i * HC + c0) = o;
    } else {
      outb[(size_t)i * HC + c0] = f2b(r[0]);
    }
  } else {
#pragma unroll
    for (int j = 0; j < VPT; j++) {
      if (auxf) auxf[(size_t)i * HC + c0 + j] = r[j];
      stf(outv, (size_t)10000 + (size_t)i * HC + c0 + j, isbf, r[j]);
    }
  }
}

// ---------------------------------------------------------------- MLP head
__global__ __launch_bounds__(256) void mlp_kernel(const float* __restrict__ x3f,
                                                  const void* __restrict__ r1w,
                                                  const void* __restrict__ r1b,
                                                  const void* __restrict__ r2w,
                                                  const void* __restrict__ r2b,
                                                  const void* __restrict__ r3w,
                                                  const void* __restrict__ r3b,
                                                  void* __restrict__ scores,
                                                  const int* __restrict__ FLAG) {
  int isbf = *FLAG;
  __shared__ float sx[64], t1[256], t2[128];
  int i = blockIdx.x, t = threadIdx.x;
  if (t < 64) sx[t] = x3f[(size_t)i * 64 + t];
  __syncthreads();
  float a = 0.f;
  for (int k = 0; k < 64; k++) a += sx[k] * ldf(r1w, (size_t)k * 256 + t, isbf);
  a += ldf(r1b, t, isbf);
  t1[t] = fmaxf(a, 0.f);
  __syncthreads();
  if (t < 128) {
    float b = 0.f;
    for (int k = 0; k < 256; k++) b += t1[k] * ldf(r2w, (size_t)k * 128 + t, isbf);
    b += ldf(r2b, t, isbf);
    t2[t] = fmaxf(b, 0.f);
  }
  __syncthreads();
  if (t < 64) {
    float v = t2[t] * ldf(r3w, t, isbf) + t2[t + 64] * ldf(r3w, t + 64, isbf);
    for (int o = 32; o; o >>= 1) v += __shfl_down(v, o);
    if (t == 0) stf(scores, i, isbf, v + ldf(r3b, 0, isbf));
  }
}

// ---------------------------------------------------------------- launch
extern "C" void kernel_launch(void* const* d_in, const int* in_sizes, int n_in,
                              void* d_out, int out_size, void* d_ws, size_t ws_size,
                              hipStream_t stream) {
  const void* x   = d_in[0];
  const int* ei   = (const int*)d_in[1];
  const void* W1  = d_in[2];
  const void* as1 = d_in[3];
  const void* ad1 = d_in[4];
  const void* b1  = d_in[5];
  const void* W2  = d_in[6];
  const void* as2 = d_in[7];
  const void* ad2 = d_in[8];
  const void* b2  = d_in[9];
  const void* W3  = d_in[10];
  const void* as3 = d_in[11];
  const void* ad3 = d_in[12];
  const void* b3  = d_in[13];
  const void* r1w = d_in[14];
  const void* r1b = d_in[15];
  const void* r2w = d_in[16];
  const void* r2b = d_in[17];
  const void* r3w = d_in[18];
  const void* r3b = d_in[19];

  char* ws = (char*)d_ws;
  size_t o = 0;
  auto alloc = [&](size_t bytes) { void* p = ws + o; o += (bytes + 255) & ~(size_t)255; return p; };
  u16* XC     = (u16*)alloc((size_t)NN * 768 * 2);
  u16* W1T    = (u16*)alloc((size_t)2048 * 768 * 2);
  u16* W2T    = (u16*)alloc((size_t)1024 * 2048 * 2);
  u16* W3T    = (u16*)alloc((size_t)64 * 1024 * 2);
  u16* Hbuf   = (u16*)alloc((size_t)NN * 2048 * 2);
  u16* Xbuf   = (u16*)alloc((size_t)NN * 2048 * 2);
  float* X3F  = (float*)alloc((size_t)NN * 64 * 4);
  float* HS   = (float*)alloc((size_t)NN * 8 * 4);
  float* HD   = (float*)alloc((size_t)NN * 8 * 4);
  int* DEG    = (int*)alloc((size_t)NN * 4);
  int* OFFS   = (int*)alloc((size_t)(NN + 1) * 4);
  int* CURSOR = (int*)alloc((size_t)NN * 4);
  int* CSR    = (int*)alloc((size_t)NTOT * 4);
  float* ALPHA = (float*)alloc((size_t)NTOT * 8 * 4);
  int* FLAG   = (int*)alloc(256);

  detect_kernel<<<1, 64, 0, stream>>>(x, FLAG);
  cvt_kernel<<<(NN * 768 + 255) / 256, 256, 0, stream>>>(x, XC, NN * 768, FLAG);

  transpose_kernel<<<dim3(2048 / 32, 768 / 32), dim3(32, 8), 0, stream>>>(W1, W1T, 768, 2048, FLAG);
  transpose_kernel<<<dim3(1024 / 32, 2048 / 32), dim3(32, 8), 0, stream>>>(W2, W2T, 2048, 1024, FLAG);
  transpose_kernel<<<dim3(64 / 32, 1024 / 32), dim3(32, 8), 0, stream>>>(W3, W3T, 1024, 64, FLAG);

  init_deg_kernel<<<(NN + 255) / 256, 256, 0, stream>>>(DEG);
  count_deg_kernel<<<(NE + 255) / 256, 256, 0, stream>>>(ei, DEG);
  scan_kernel<<<1, 1024, 0, stream>>>(DEG, OFFS, CURSOR, NN);
  scatter_kernel<<<(NTOT + 255) / 256, 256, 0, stream>>>(ei, CURSOR, CSR);

  const int MT = (NN + 127) / 128;  // 79

  // ---- layer 1: 768 -> 8 x 256
  gemm_kernel<128, 128, 2, 2><<<MT * 16, 256, 0, stream>>>(XC, W1T, Hbuf, NN, 768, 2048, 16);
  dot_av_kernel<<<(NN * 8 + 3) / 4, 256, 0, stream>>>(Hbuf, as1, ad1, HS, HD, 8, 256, NN, FLAG);
  softmax_kernel<<<(NN * 8 + 255) / 256, 256, 0, stream>>>(CSR, OFFS, HS, HD, ALPHA, 8, NN);
  aggregate_kernel<2048, 8, 256><<<NN, 256, 0, stream>>>(Hbuf, ALPHA, CSR, OFFS, b1, Xbuf, nullptr, nullptr, 8, 256, 1, FLAG);

  // ---- layer 2: 2048 -> 4 x 256
  gemm_kernel<128, 128, 2, 2><<<MT * 8, 256, 0, stream>>>(Xbuf, W2T, Hbuf, NN, 2048, 1024, 8);
  dot_av_kernel<<<(NN * 4 + 3) / 4, 256, 0, stream>>>(Hbuf, as2, ad2, HS, HD, 4, 256, NN, FLAG);
  softmax_kernel<<<(NN * 4 + 255) / 256, 256, 0, stream>>>(CSR, OFFS, HS, HD, ALPHA, 4, NN);
  aggregate_kernel<1024, 4, 256><<<NN, 256, 0, stream>>>(Hbuf, ALPHA, CSR, OFFS, b2, Xbuf, nullptr, nullptr, 4, 256, 1, FLAG);

  // ---- layer 3: 1024 -> 1 x 64
  gemm_kernel<128, 64, 4, 1><<<MT, 256, 0, stream>>>(Xbuf, W3T, Hbuf, NN, 1024, 64, 1);
  dot_av_kernel<<<(NN + 3) / 4, 256, 0, stream>>>(Hbuf, as3, ad3, HS, HD, 1, 64, NN, FLAG);
  softmax_kernel<<<(NN + 255) / 256, 256, 0, stream>>>(CSR, OFFS, HS, HD, ALPHA, 1, NN);
  aggregate_kernel<64, 1, 64><<<NN, 64, 0, stream>>>(Hbuf, ALPHA, CSR, OFFS, b3, nullptr, d_out, X3F, 1, 64, 0, FLAG);

  // ---- reasoning MLP
  mlp_kernel<<<NN, 256, 0, stream>>>(X3F, r1w, r1b, r2w, r2b, r3w, r3b, d_out, FLAG);
}

// Round 4
// 499.380 us; speedup vs baseline: 1.6141x; 1.1256x over previous
//
#include <hip/hip_runtime.h>
#include <stdint.h>

typedef unsigned short u16;
using s16x8 = __attribute__((ext_vector_type(8))) short;
using f32x4 = __attribute__((ext_vector_type(4))) float;
using u16x8 = __attribute__((ext_vector_type(8))) unsigned short;
using u16x4 = __attribute__((ext_vector_type(4))) unsigned short;

#define DEVINL __device__ __forceinline__

DEVINL float b2f(u16 u) { return __uint_as_float(((uint32_t)u) << 16); }
DEVINL u16 f2b(float f) {
  uint32_t x = __float_as_uint(f);
  return (u16)((x + 0x7fffu + ((x >> 16) & 1u)) >> 16);
}
// dtype-agnostic load/store: isbf=1 -> bf16 (u16), else fp32
DEVINL float ldf(const void* p, size_t i, int isbf) {
  return isbf ? b2f(((const u16*)p)[i]) : ((const float*)p)[i];
}
DEVINL void stf(void* p, size_t i, int isbf, float v) {
  if (isbf) ((u16*)p)[i] = f2b(v);
  else      ((float*)p)[i] = v;
}

typedef __attribute__((address_space(1))) const void gvoid;
typedef __attribute__((address_space(3))) void lvoid;
DEVINL void gload_lds16(const u16* g, u16* l) {
  __builtin_amdgcn_global_load_lds((gvoid*)g, (lvoid*)l, 16, 0, 0);
}

constexpr int NN = 10000;     // nodes
constexpr int NE = 80000;     // edges (no self loops)
constexpr int NTOT = 90000;   // edges + self loops

// ---------------------------------------------------------------- dtype detect
__global__ void detect_kernel(const void* __restrict__ x, int* __restrict__ flag) {
  int lane = threadIdx.x;  // 64
  u16 w = ((const u16*)x)[lane * 97 + 13];
  int e = (w >> 7) & 0xFF;
  int sane = (e >= 0x50 && e <= 0x8A) ? 1 : 0;
  unsigned long long b = __ballot(sane);
  if (lane == 0) flag[0] = (__popcll(b) >= 56) ? 1 : 0;
}

// canonicalize x -> bf16
__global__ void cvt_kernel(const void* __restrict__ in, u16* __restrict__ out,
                           int n, const int* __restrict__ FLAG) {
  int isbf = *FLAG;
  int i = blockIdx.x * 256 + threadIdx.x;
  if (i >= n) return;
  out[i] = isbf ? ((const u16*)in)[i] : f2b(((const float*)in)[i]);
}

// ---------------------------------------------------------------- transpose
__global__ void transpose_kernel(const void* __restrict__ in, u16* __restrict__ out,
                                 int R, int C, const int* __restrict__ FLAG) {
  int isbf = *FLAG;
  __shared__ float tile[32][33];
  int bx = blockIdx.x * 32, by = blockIdx.y * 32;
  int tx = threadIdx.x, ty = threadIdx.y;  // (32,8)
  for (int j = 0; j < 32; j += 8) {
    int r = by + ty + j, c = bx + tx;
    if (r < R && c < C) tile[ty + j][tx] = ldf(in, (size_t)r * C + c, isbf);
  }
  __syncthreads();
  for (int j = 0; j < 32; j += 8) {
    int r = bx + ty + j, c = by + tx;
    if (r < C && c < R) out[(size_t)r * R + c] = f2b(tile[tx][ty + j]);
  }
}

// ---------------------------------------------------------------- CSR build
__global__ void init_deg_kernel(int* __restrict__ deg) {
  int i = blockIdx.x * blockDim.x + threadIdx.x;
  if (i < NN) deg[i] = 1;  // self loop
}

__global__ void count_deg_kernel(const int* __restrict__ ei, int* __restrict__ deg) {
  int e = blockIdx.x * blockDim.x + threadIdx.x;
  if (e < NE) atomicAdd(&deg[ei[NE + e]], 1);
}

__global__ __launch_bounds__(1024) void scan_kernel(const int* __restrict__ deg,
                                                    int* __restrict__ offs,
                                                    int* __restrict__ cursor, int n) {
  __shared__ int buf[1024];
  __shared__ int carry;
  int tid = threadIdx.x;
  if (tid == 0) carry = 0;
  __syncthreads();
  for (int base = 0; base < n; base += 1024) {
    int idx = base + tid;
    int v = (idx < n) ? deg[idx] : 0;
    buf[tid] = v;
    __syncthreads();
    for (int off = 1; off < 1024; off <<= 1) {
      int add = (tid >= off) ? buf[tid - off] : 0;
      __syncthreads();
      buf[tid] += add;
      __syncthreads();
    }
    int inc = buf[tid] + carry;
    if (idx < n) { offs[idx + 1] = inc; cursor[idx] = inc - v; }
    __syncthreads();
    if (tid == 0) carry += buf[1023];
    __syncthreads();
  }
  if (tid == 0) offs[0] = 0;
}

__global__ void scatter_kernel(const int* __restrict__ ei, int* __restrict__ cursor,
                               int* __restrict__ csr_src) {
  int e = blockIdx.x * blockDim.x + threadIdx.x;
  if (e >= NTOT) return;
  int s, d;
  if (e < NE) { s = ei[e]; d = ei[NE + e]; }
  else        { s = e - NE; d = s; }
  int pos = atomicAdd(&cursor[d], 1);
  csr_src[pos] = s;
}

// ---------------------------------------------------------------- GEMM (bf16 MFMA)
// C[M,N] = A[M,K] * Bt[N,K]^T. m97 structure: global_load_lds width-16 staging,
// linear LDS, 2 barriers/K-step, XCD-bijective remap, LDS-staged coalesced
// C store with optional fused bias+relu epilogue.
template <int BM, int BN, int WM, int WN>
__global__ __launch_bounds__(256) void gemm_kernel(const u16* __restrict__ A,
                                                   const u16* __restrict__ Bt,
                                                   u16* __restrict__ C,
                                                   int M, int K, int N, int nN,
                                                   const void* __restrict__ bias,
                                                   int do_relu,
                                                   const int* __restrict__ FLAG) {
  constexpr int BK = 64;             // 128 B per LDS row
  constexpr int WTM = BM / WM, WTN = BN / WN;
  constexpr int FM = WTM / 16, FN = WTN / 16;
  constexpr int ACH = BM / 32;       // 1KB staging chunks per wave (A)
  constexpr int BCH = BN / 32;

  __shared__ u16 smem[(BM + BN) * BK];
  u16* lA = smem;
  u16* lB = smem + BM * BK;

  int tid = threadIdx.x;
  int lane = tid & 63, wid = tid >> 6;
  int wm = wid / WN, wn = wid % WN;
  int isbf = bias ? *FLAG : 0;

  // bijective XCD remap (m204): each XCD owns a contiguous wgid chunk;
  // wgid%nN is the N tile (fastest) -> B panel stays L2-resident per XCD.
  int nwg = gridDim.x;
  int q = nwg >> 3, r = nwg & 7;
  int xcd = blockIdx.x & 7, pos = blockIdx.x >> 3;
  int wgid = (xcd < r ? xcd * (q + 1) : r * (q + 1) + (xcd - r) * q) + pos;
  int bm0 = (wgid / nN) * BM, bn0 = (wgid % nN) * BN;

  int srow = lane >> 3;          // staging: row within 8-row chunk
  int scol = (lane & 7) * 8;     // staging: u16 col (16B granules)

  f32x4 acc[FM][FN];
#pragma unroll
  for (int m = 0; m < FM; m++)
#pragma unroll
    for (int n = 0; n < FN; n++) acc[m][n] = (f32x4){0.f, 0.f, 0.f, 0.f};

  for (int k0 = 0; k0 < K; k0 += BK) {
    // ---- stage tile via global_load_lds (linear LDS, wave-uniform dest)
#pragma unroll
    for (int i = 0; i < ACH; i++) {
      int c = wid * ACH + i;
      int row = c * 8 + srow;
      int grow = bm0 + row;
      if (grow > M - 1) grow = M - 1;
      gload_lds16(A + (size_t)grow * K + k0 + scol, lA + c * 512);
    }
#pragma unroll
    for (int i = 0; i < BCH; i++) {
      int c = wid * BCH + i;
      int row = c * 8 + srow;
      gload_lds16(Bt + (size_t)(bn0 + row) * K + k0 + scol, lB + c * 512);
    }
    __syncthreads();  // drains vmcnt(0) -> LDS tile ready

    // ---- MFMA over BK (2 x k=32 steps)
#pragma unroll
    for (int ks = 0; ks < 2; ks++) {
      int kb = ks * 64 + ((lane >> 4) << 4);  // byte offset within 128B row
      s16x8 af[FM], bf[FN];
#pragma unroll
      for (int m = 0; m < FM; m++) {
        int row = wm * WTM + m * 16 + (lane & 15);
        af[m] = *(const s16x8*)((const char*)lA + row * 128 + kb);
      }
#pragma unroll
      for (int n = 0; n < FN; n++) {
        int row = wn * WTN + n * 16 + (lane & 15);
        bf[n] = *(const s16x8*)((const char*)lB + row * 128 + kb);
      }
#pragma unroll
      for (int m = 0; m < FM; m++)
#pragma unroll
        for (int n = 0; n < FN; n++)
          acc[m][n] = __builtin_amdgcn_mfma_f32_16x16x32_bf16(af[m], bf[n], acc[m][n], 0, 0, 0);
    }
    __syncthreads();  // LDS consumed; safe to restage
  }

  // ---- epilogue: bias/relu, stage C tile in LDS (bf16), coalesced 16B stores
  u16* lC = smem;  // BM*BN u16 <= (BM+BN)*BK for our configs
  int r0 = (lane >> 4) * 4;
#pragma unroll
  for (int m = 0; m < FM; m++)
#pragma unroll
    for (int n = 0; n < FN; n++)
#pragma unroll
      for (int rr = 0; rr < 4; rr++) {
        int row = wm * WTM + m * 16 + r0 + rr;
        int col = wn * WTN + n * 16 + (lane & 15);
        float v = acc[m][n][rr];
        if (bias) v += ldf(bias, bn0 + col, isbf);
        if (do_relu) v = fmaxf(v, 0.f);
        lC[row * BN + col] = f2b(v);
      }
  __syncthreads();
  constexpr int CHUNKS = BM * BN / 2048;  // 16B chunks per thread
  constexpr int CPR = BN / 8;             // chunks per C row
#pragma unroll
  for (int j = 0; j < CHUNKS; j++) {
    int idx = j * 256 + tid;
    int row = idx / CPR, colb = (idx % CPR) * 16;
    int grow = bm0 + row;
    if (grow < M) {
      int4 v = *(const int4*)((const char*)lC + idx * 16);
      *(int4*)((char*)C + ((size_t)grow * N + bn0) * 2 + colb) = v;
    }
  }
}

// ---------------------------------------------------------------- hs/hd dots
__global__ __launch_bounds__(256) void dot_av_kernel(const u16* __restrict__ h,
                                                     const void* __restrict__ asrc,
                                                     const void* __restrict__ adst,
                                                     float* __restrict__ hs,
                                                     float* __restrict__ hd,
                                                     int H, int C, int n,
                                                     const int* __restrict__ FLAG) {
  int isbf = *FLAG;
  int wid = threadIdx.x >> 6, lane = threadIdx.x & 63;
  int pair = blockIdx.x * 4 + wid;
  if (pair >= n * H) return;
  int node = pair / H, head = pair % H;
  const u16* hp = h + (size_t)node * H * C + head * C;
  float s = 0.f, d = 0.f;
  int c0 = lane * 4;
  if (c0 < C) {
    u16x4 v = *(const u16x4*)(hp + c0);
#pragma unroll
    for (int j = 0; j < 4; j++) {
      float f = b2f(v[j]);
      s += f * ldf(asrc, (size_t)head * C + c0 + j, isbf);
      d += f * ldf(adst, (size_t)head * C + c0 + j, isbf);
    }
  }
  for (int o = 32; o; o >>= 1) { s += __shfl_down(s, o); d += __shfl_down(d, o); }
  if (lane == 0) { hs[pair] = s; hd[pair] = d; }
}

// ---------------------------------------------------------------- edge softmax
__global__ void softmax_kernel(const int* __restrict__ csr_src, const int* __restrict__ offs,
                               const float* __restrict__ hs, const float* __restrict__ hd,
                               float* __restrict__ alpha, int H, int n) {
  int idx = blockIdx.x * blockDim.x + threadIdx.x;
  if (idx >= n * H) return;
  int i = idx / H, hh = idx % H;
  float hdv = hd[idx];
  int p0 = offs[i], p1 = offs[i + 1];
  float m = -1e30f;
  for (int p = p0; p < p1; ++p) {
    float e = hs[csr_src[p] * H + hh] + hdv;
    e = e > 0.f ? e : 0.2f * e;
    m = fmaxf(m, e);
  }
  float den = 0.f;
  for (int p = p0; p < p1; ++p) {
    float e = hs[csr_src[p] * H + hh] + hdv;
    e = e > 0.f ? e : 0.2f * e;
    float pe = __expf(e - m);
    alpha[(size_t)p * H + hh] = pe;
    den += pe;
  }
  float inv = 1.f / (den + 1e-16f);
  for (int p = p0; p < p1; ++p) alpha[(size_t)p * H + hh] *= inv;
}

// ---------------------------------------------------------------- aggregation
template <int HC, int VPT, int TPB>
__global__ __launch_bounds__(TPB) void aggregate_kernel(
    const u16* __restrict__ h, const float* __restrict__ alpha,
    const int* __restrict__ csr_src, const int* __restrict__ offs,
    const void* __restrict__ bias, u16* __restrict__ outb, void* __restrict__ outv,
    int H, int C, int do_elu, const int* __restrict__ FLAG) {
  int isbf = *FLAG;
  int i = blockIdx.x;
  int t = threadIdx.x;
  int c0 = t * VPT;
  int head = c0 / C;
  float acc[VPT];
#pragma unroll
  for (int j = 0; j < VPT; j++) acc[j] = 0.f;
  int p0 = offs[i], p1 = offs[i + 1];
  for (int p = p0; p < p1; ++p) {
    int s = csr_src[p];
    float al = alpha[(size_t)p * H + head];
    const u16* hp = h + (size_t)s * HC + c0;
    if constexpr (VPT == 8) {
      u16x8 v = *(const u16x8*)hp;
#pragma unroll
      for (int j = 0; j < 8; j++) acc[j] += al * b2f(v[j]);
    } else if constexpr (VPT == 4) {
      u16x4 v = *(const u16x4*)hp;
#pragma unroll
      for (int j = 0; j < 4; j++) acc[j] += al * b2f(v[j]);
    } else {
      acc[0] += al * b2f(hp[0]);
    }
  }
  float r[VPT];
#pragma unroll
  for (int j = 0; j < VPT; j++) {
    r[j] = acc[j] + ldf(bias, c0 + j, isbf);
    if (do_elu) r[j] = r[j] > 0.f ? r[j] : expm1f(r[j]);
  }
  if (outb) {
    if constexpr (VPT == 8) {
      u16x8 o;
#pragma unroll
      for (int j = 0; j < 8; j++) o[j] = f2b(r[j]);
      *(u16x8*)(outb + (size_t)i * HC + c0) = o;
    } else if constexpr (VPT == 4) {
      u16x4 o;
#pragma unroll
      for (int j = 0; j < 4; j++) o[j] = f2b(r[j]);
      *(u16x4*)(outb + (size_t)i * HC + c0) = o;
    } else {
      outb[(size_t)i * HC + c0] = f2b(r[0]);
    }
  }
  if (outv) {
#pragma unroll
    for (int j = 0; j < VPT; j++)
      stf(outv, (size_t)10000 + (size_t)i * HC + c0 + j, isbf, r[j]);
  }
}

// ---------------------------------------------------------------- final dot (h2[128] . r3w + r3b)
__global__ __launch_bounds__(256) void dot128_kernel(const u16* __restrict__ h2,
                                                     const void* __restrict__ r3w,
                                                     const void* __restrict__ r3b,
                                                     void* __restrict__ scores,
                                                     const int* __restrict__ FLAG) {
  int isbf = *FLAG;
  int wid = threadIdx.x >> 6, lane = threadIdx.x & 63;
  int i = blockIdx.x * 4 + wid;
  if (i >= NN) return;
  const u16* hp = h2 + (size_t)i * 128;
  float v = b2f(hp[lane]) * ldf(r3w, lane, isbf) +
            b2f(hp[lane + 64]) * ldf(r3w, lane + 64, isbf);
  for (int o = 32; o; o >>= 1) v += __shfl_down(v, o);
  if (lane == 0) stf(scores, i, isbf, v + ldf(r3b, 0, isbf));
}

// ---------------------------------------------------------------- launch
extern "C" void kernel_launch(void* const* d_in, const int* in_sizes, int n_in,
                              void* d_out, int out_size, void* d_ws, size_t ws_size,
                              hipStream_t stream) {
  const void* x   = d_in[0];
  const int* ei   = (const int*)d_in[1];
  const void* W1  = d_in[2];
  const void* as1 = d_in[3];
  const void* ad1 = d_in[4];
  const void* b1  = d_in[5];
  const void* W2  = d_in[6];
  const void* as2 = d_in[7];
  const void* ad2 = d_in[8];
  const void* b2  = d_in[9];
  const void* W3  = d_in[10];
  const void* as3 = d_in[11];
  const void* ad3 = d_in[12];
  const void* b3  = d_in[13];
  const void* r1w = d_in[14];
  const void* r1b = d_in[15];
  const void* r2w = d_in[16];
  const void* r2b = d_in[17];
  const void* r3w = d_in[18];
  const void* r3b = d_in[19];

  char* ws = (char*)d_ws;
  size_t o = 0;
  auto alloc = [&](size_t bytes) { void* p = ws + o; o += (bytes + 255) & ~(size_t)255; return p; };
  u16* XC     = (u16*)alloc((size_t)NN * 768 * 2);
  u16* W1T    = (u16*)alloc((size_t)2048 * 768 * 2);
  u16* W2T    = (u16*)alloc((size_t)1024 * 2048 * 2);
  u16* W3T    = (u16*)alloc((size_t)64 * 1024 * 2);
  u16* R1T    = (u16*)alloc((size_t)256 * 64 * 2);
  u16* R2T    = (u16*)alloc((size_t)128 * 256 * 2);
  u16* Hbuf   = (u16*)alloc((size_t)NN * 2048 * 2);
  u16* Xbuf   = (u16*)alloc((size_t)NN * 2048 * 2);
  u16* X3B    = (u16*)alloc((size_t)NN * 64 * 2);
  u16* H1B    = (u16*)alloc((size_t)NN * 256 * 2);
  u16* H2B    = (u16*)alloc((size_t)NN * 128 * 2);
  float* HS   = (float*)alloc((size_t)NN * 8 * 4);
  float* HD   = (float*)alloc((size_t)NN * 8 * 4);
  int* DEG    = (int*)alloc((size_t)NN * 4);
  int* OFFS   = (int*)alloc((size_t)(NN + 1) * 4);
  int* CURSOR = (int*)alloc((size_t)NN * 4);
  int* CSR    = (int*)alloc((size_t)NTOT * 4);
  float* ALPHA = (float*)alloc((size_t)NTOT * 8 * 4);
  int* FLAG   = (int*)alloc(256);

  detect_kernel<<<1, 64, 0, stream>>>(x, FLAG);
  cvt_kernel<<<(NN * 768 + 255) / 256, 256, 0, stream>>>(x, XC, NN * 768, FLAG);

  transpose_kernel<<<dim3(2048 / 32, 768 / 32), dim3(32, 8), 0, stream>>>(W1, W1T, 768, 2048, FLAG);
  transpose_kernel<<<dim3(1024 / 32, 2048 / 32), dim3(32, 8), 0, stream>>>(W2, W2T, 2048, 1024, FLAG);
  transpose_kernel<<<dim3(64 / 32, 1024 / 32), dim3(32, 8), 0, stream>>>(W3, W3T, 1024, 64, FLAG);
  transpose_kernel<<<dim3(256 / 32, 64 / 32), dim3(32, 8), 0, stream>>>(r1w, R1T, 64, 256, FLAG);
  transpose_kernel<<<dim3(128 / 32, 256 / 32), dim3(32, 8), 0, stream>>>(r2w, R2T, 256, 128, FLAG);

  init_deg_kernel<<<(NN + 255) / 256, 256, 0, stream>>>(DEG);
  count_deg_kernel<<<(NE + 255) / 256, 256, 0, stream>>>(ei, DEG);
  scan_kernel<<<1, 1024, 0, stream>>>(DEG, OFFS, CURSOR, NN);
  scatter_kernel<<<(NTOT + 255) / 256, 256, 0, stream>>>(ei, CURSOR, CSR);

  const int MT = (NN + 127) / 128;   // 79
  const int MT64 = (NN + 63) / 64;   // 157

  // ---- layer 1: 768 -> 8 x 256
  gemm_kernel<128, 128, 2, 2><<<MT * 16, 256, 0, stream>>>(XC, W1T, Hbuf, NN, 768, 2048, 16, nullptr, 0, FLAG);
  dot_av_kernel<<<(NN * 8 + 3) / 4, 256, 0, stream>>>(Hbuf, as1, ad1, HS, HD, 8, 256, NN, FLAG);
  softmax_kernel<<<(NN * 8 + 255) / 256, 256, 0, stream>>>(CSR, OFFS, HS, HD, ALPHA, 8, NN);
  aggregate_kernel<2048, 8, 256><<<NN, 256, 0, stream>>>(Hbuf, ALPHA, CSR, OFFS, b1, Xbuf, nullptr, 8, 256, 1, FLAG);

  // ---- layer 2: 2048 -> 4 x 256
  gemm_kernel<128, 128, 2, 2><<<MT * 8, 256, 0, stream>>>(Xbuf, W2T, Hbuf, NN, 2048, 1024, 8, nullptr, 0, FLAG);
  dot_av_kernel<<<(NN * 4 + 3) / 4, 256, 0, stream>>>(Hbuf, as2, ad2, HS, HD, 4, 256, NN, FLAG);
  softmax_kernel<<<(NN * 4 + 255) / 256, 256, 0, stream>>>(CSR, OFFS, HS, HD, ALPHA, 4, NN);
  aggregate_kernel<1024, 4, 256><<<NN, 256, 0, stream>>>(Hbuf, ALPHA, CSR, OFFS, b2, Xbuf, nullptr, 4, 256, 1, FLAG);

  // ---- layer 3: 1024 -> 1 x 64
  gemm_kernel<128, 64, 4, 1><<<MT, 256, 0, stream>>>(Xbuf, W3T, Hbuf, NN, 1024, 64, 1, nullptr, 0, FLAG);
  dot_av_kernel<<<(NN + 3) / 4, 256, 0, stream>>>(Hbuf, as3, ad3, HS, HD, 1, 64, NN, FLAG);
  softmax_kernel<<<(NN + 255) / 256, 256, 0, stream>>>(CSR, OFFS, HS, HD, ALPHA, 1, NN);
  aggregate_kernel<64, 1, 64><<<NN, 64, 0, stream>>>(Hbuf, ALPHA, CSR, OFFS, b3, X3B, d_out, 1, 64, 0, FLAG);

  // ---- reasoning MLP as MFMA GEMMs + final dot
  gemm_kernel<64, 64, 2, 2><<<MT64 * 4, 256, 0, stream>>>(X3B, R1T, H1B, NN, 64, 256, 4, r1b, 1, FLAG);
  gemm_kernel<64, 64, 2, 2><<<MT64 * 2, 256, 0, stream>>>(H1B, R2T, H2B, NN, 256, 128, 2, r2b, 1, FLAG);
  dot128_kernel<<<(NN + 3) / 4, 256, 0, stream>>>(H2B, r3w, r3b, d_out, FLAG);
}

// Round 5
// 453.310 us; speedup vs baseline: 1.7781x; 1.1016x over previous
//
#include <hip/hip_runtime.h>
#include <stdint.h>

typedef unsigned short u16;
using s16x8 = __attribute__((ext_vector_type(8))) short;
using f32x4 = __attribute__((ext_vector_type(4))) float;
using u16x8 = __attribute__((ext_vector_type(8))) unsigned short;
using u16x4 = __attribute__((ext_vector_type(4))) unsigned short;

#define DEVINL __device__ __forceinline__

DEVINL float b2f(u16 u) { return __uint_as_float(((uint32_t)u) << 16); }
DEVINL u16 f2b(float f) {
  uint32_t x = __float_as_uint(f);
  return (u16)((x + 0x7fffu + ((x >> 16) & 1u)) >> 16);
}
// dtype-agnostic load/store: isbf=1 -> bf16 (u16), else fp32
DEVINL float ldf(const void* p, size_t i, int isbf) {
  return isbf ? b2f(((const u16*)p)[i]) : ((const float*)p)[i];
}
DEVINL void stf(void* p, size_t i, int isbf, float v) {
  if (isbf) ((u16*)p)[i] = f2b(v);
  else      ((float*)p)[i] = v;
}

typedef __attribute__((address_space(1))) const void gvoid;
typedef __attribute__((address_space(3))) void lvoid;
DEVINL void gload_lds16(const u16* g, u16* l) {
  __builtin_amdgcn_global_load_lds((gvoid*)g, (lvoid*)l, 16, 0, 0);
}

constexpr int NN = 10000;     // nodes
constexpr int NE = 80000;     // edges (no self loops)
constexpr int NTOT = 90000;   // edges + self loops

// ---------------------------------------------------------------- dtype detect
__global__ void detect_kernel(const void* __restrict__ x, int* __restrict__ flag) {
  int lane = threadIdx.x;  // 64
  u16 w = ((const u16*)x)[lane * 97 + 13];
  int e = (w >> 7) & 0xFF;
  int sane = (e >= 0x50 && e <= 0x8A) ? 1 : 0;
  unsigned long long b = __ballot(sane);
  if (lane == 0) flag[0] = (__popcll(b) >= 56) ? 1 : 0;
}

// canonicalize x -> bf16
__global__ void cvt_kernel(const void* __restrict__ in, u16* __restrict__ out,
                           int n, const int* __restrict__ FLAG) {
  int isbf = *FLAG;
  int i = blockIdx.x * 256 + threadIdx.x;
  if (i >= n) return;
  out[i] = isbf ? ((const u16*)in)[i] : f2b(((const float*)in)[i]);
}

// ---------------------------------------------------------------- transpose
__global__ void transpose_kernel(const void* __restrict__ in, u16* __restrict__ out,
                                 int R, int C, const int* __restrict__ FLAG) {
  int isbf = *FLAG;
  __shared__ float tile[32][33];
  int bx = blockIdx.x * 32, by = blockIdx.y * 32;
  int tx = threadIdx.x, ty = threadIdx.y;  // (32,8)
  for (int j = 0; j < 32; j += 8) {
    int r = by + ty + j, c = bx + tx;
    if (r < R && c < C) tile[ty + j][tx] = ldf(in, (size_t)r * C + c, isbf);
  }
  __syncthreads();
  for (int j = 0; j < 32; j += 8) {
    int r = bx + ty + j, c = by + tx;
    if (r < C && c < R) out[(size_t)r * R + c] = f2b(tile[tx][ty + j]);
  }
}

// ---------------------------------------------------------------- CSR build
__global__ void init_deg_kernel(int* __restrict__ deg) {
  int i = blockIdx.x * blockDim.x + threadIdx.x;
  if (i < NN) deg[i] = 1;  // self loop
}

__global__ void count_deg_kernel(const int* __restrict__ ei, int* __restrict__ deg) {
  int e = blockIdx.x * blockDim.x + threadIdx.x;
  if (e < NE) atomicAdd(&deg[ei[NE + e]], 1);
}

__global__ __launch_bounds__(1024) void scan_kernel(const int* __restrict__ deg,
                                                    int* __restrict__ offs,
                                                    int* __restrict__ cursor, int n) {
  __shared__ int buf[1024];
  __shared__ int carry;
  int tid = threadIdx.x;
  if (tid == 0) carry = 0;
  __syncthreads();
  for (int base = 0; base < n; base += 1024) {
    int idx = base + tid;
    int v = (idx < n) ? deg[idx] : 0;
    buf[tid] = v;
    __syncthreads();
    for (int off = 1; off < 1024; off <<= 1) {
      int add = (tid >= off) ? buf[tid - off] : 0;
      __syncthreads();
      buf[tid] += add;
      __syncthreads();
    }
    int inc = buf[tid] + carry;
    if (idx < n) { offs[idx + 1] = inc; cursor[idx] = inc - v; }
    __syncthreads();
    if (tid == 0) carry += buf[1023];
    __syncthreads();
  }
  if (tid == 0) offs[0] = 0;
}

__global__ void scatter_kernel(const int* __restrict__ ei, int* __restrict__ cursor,
                               int* __restrict__ csr_src) {
  int e = blockIdx.x * blockDim.x + threadIdx.x;
  if (e >= NTOT) return;
  int s, d;
  if (e < NE) { s = ei[e]; d = ei[NE + e]; }
  else        { s = e - NE; d = s; }
  int pos = atomicAdd(&cursor[d], 1);
  csr_src[pos] = s;
}

// ---------------------------------------------------------------- GEMM (bf16 MFMA)
// C[M,N] = A[M,K] * Bt[N,K]^T. m97 structure + T2 both-sides swizzle:
// linear LDS dest (global_load_lds), pre-swizzled per-lane global source
// granule (lane&7)^(lane>>3), XOR-swizzled ds_read. XCD-bijective remap,
// LDS-staged coalesced C store, optional fused bias+relu.
template <int BM, int BN, int WM, int WN>
__global__ __launch_bounds__(256) void gemm_kernel(const u16* __restrict__ A,
                                                   const u16* __restrict__ Bt,
                                                   u16* __restrict__ C,
                                                   int M, int K, int N, int nN,
                                                   const void* __restrict__ bias,
                                                   int do_relu,
                                                   const int* __restrict__ FLAG) {
  constexpr int BK = 64;             // 128 B per LDS row
  constexpr int WTM = BM / WM, WTN = BN / WN;
  constexpr int FM = WTM / 16, FN = WTN / 16;
  constexpr int ACH = BM / 32;       // 1KB staging chunks per wave (A)
  constexpr int BCH = BN / 32;

  __shared__ u16 smem[(BM + BN) * BK];
  u16* lA = smem;
  u16* lB = smem + BM * BK;

  int tid = threadIdx.x;
  int lane = tid & 63, wid = tid >> 6;
  int wm = wid / WN, wn = wid % WN;
  int isbf = bias ? *FLAG : 0;

  // bijective XCD remap (m204)
  int nwg = gridDim.x;
  int q = nwg >> 3, r = nwg & 7;
  int xcd = blockIdx.x & 7, pos = blockIdx.x >> 3;
  int wgid = (xcd < r ? xcd * (q + 1) : r * (q + 1) + (xcd - r) * q) + pos;
  int bm0 = (wgid / nN) * BM, bn0 = (wgid % nN) * BN;

  int srow = lane >> 3;                               // row within 8-row chunk
  int scol = ((lane & 7) ^ (lane >> 3)) << 3;         // SWIZZLED source col (u16)

  f32x4 acc[FM][FN];
#pragma unroll
  for (int m = 0; m < FM; m++)
#pragma unroll
    for (int n = 0; n < FN; n++) acc[m][n] = (f32x4){0.f, 0.f, 0.f, 0.f};

  for (int k0 = 0; k0 < K; k0 += BK) {
    // ---- stage tile: linear LDS dest + swizzled global source (rule #21)
#pragma unroll
    for (int i = 0; i < ACH; i++) {
      int c = wid * ACH + i;
      int row = c * 8 + srow;
      int grow = bm0 + row;
      if (grow > M - 1) grow = M - 1;
      gload_lds16(A + (size_t)grow * K + k0 + scol, lA + c * 512);
    }
#pragma unroll
    for (int i = 0; i < BCH; i++) {
      int c = wid * BCH + i;
      int row = c * 8 + srow;
      gload_lds16(Bt + (size_t)(bn0 + row) * K + k0 + scol, lB + c * 512);
    }
    __syncthreads();  // drains vmcnt(0) -> LDS tile ready

    // ---- MFMA over BK (2 x k=32 steps), swizzled reads
    int swz = (lane & 7) << 4;
#pragma unroll
    for (int ks = 0; ks < 2; ks++) {
      int kb = ks * 64 + ((lane >> 4) << 4);  // linear byte offset in 128B row
      s16x8 af[FM], bf[FN];
#pragma unroll
      for (int m = 0; m < FM; m++) {
        int row = wm * WTM + m * 16 + (lane & 15);
        af[m] = *(const s16x8*)((const char*)lA + row * 128 + (kb ^ swz));
      }
#pragma unroll
      for (int n = 0; n < FN; n++) {
        int row = wn * WTN + n * 16 + (lane & 15);
        bf[n] = *(const s16x8*)((const char*)lB + row * 128 + (kb ^ swz));
      }
#pragma unroll
      for (int m = 0; m < FM; m++)
#pragma unroll
        for (int n = 0; n < FN; n++)
          acc[m][n] = __builtin_amdgcn_mfma_f32_16x16x32_bf16(af[m], bf[n], acc[m][n], 0, 0, 0);
    }
    __syncthreads();  // LDS consumed; safe to restage
  }

  // ---- epilogue: bias/relu, stage C tile in LDS (bf16), coalesced 16B stores
  u16* lC = smem;  // BM*BN u16 <= (BM+BN)*BK for our configs
  int r0 = (lane >> 4) * 4;
#pragma unroll
  for (int m = 0; m < FM; m++)
#pragma unroll
    for (int n = 0; n < FN; n++)
#pragma unroll
      for (int rr = 0; rr < 4; rr++) {
        int row = wm * WTM + m * 16 + r0 + rr;
        int col = wn * WTN + n * 16 + (lane & 15);
        float v = acc[m][n][rr];
        if (bias) v += ldf(bias, bn0 + col, isbf);
        if (do_relu) v = fmaxf(v, 0.f);
        lC[row * BN + col] = f2b(v);
      }
  __syncthreads();
  constexpr int CHUNKS = BM * BN / 2048;  // 16B chunks per thread
  constexpr int CPR = BN / 8;             // chunks per C row
#pragma unroll
  for (int j = 0; j < CHUNKS; j++) {
    int idx = j * 256 + tid;
    int row = idx / CPR, colb = (idx % CPR) * 16;
    int grow = bm0 + row;
    if (grow < M) {
      int4 v = *(const int4*)((const char*)lC + idx * 16);
      *(int4*)((char*)C + ((size_t)grow * N + bn0) * 2 + colb) = v;
    }
  }
}

// ---------------------------------------------------------------- hs/hd dots
__global__ __launch_bounds__(256) void dot_av_kernel(const u16* __restrict__ h,
                                                     const void* __restrict__ asrc,
                                                     const void* __restrict__ adst,
                                                     float* __restrict__ hs,
                                                     float* __restrict__ hd,
                                                     int H, int C, int n,
                                                     const int* __restrict__ FLAG) {
  int isbf = *FLAG;
  int wid = threadIdx.x >> 6, lane = threadIdx.x & 63;
  int pair = blockIdx.x * 4 + wid;
  if (pair >= n * H) return;
  int node = pair / H, head = pair % H;
  const u16* hp = h + (size_t)node * H * C + head * C;
  float s = 0.f, d = 0.f;
  int c0 = lane * 4;
  if (c0 < C) {
    u16x4 v = *(const u16x4*)(hp + c0);
#pragma unroll
    for (int j = 0; j < 4; j++) {
      float f = b2f(v[j]);
      s += f * ldf(asrc, (size_t)head * C + c0 + j, isbf);
      d += f * ldf(adst, (size_t)head * C + c0 + j, isbf);
    }
  }
  for (int o = 32; o; o >>= 1) { s += __shfl_down(s, o); d += __shfl_down(d, o); }
  if (lane == 0) { hs[pair] = s; hd[pair] = d; }
}

// ---------------------------------------------------------------- edge softmax
// pass1 caches e in alpha (single scattered hs gather), then exp/sum, normalize.
__global__ void softmax_kernel(const int* __restrict__ csr_src, const int* __restrict__ offs,
                               const float* __restrict__ hs, const float* __restrict__ hd,
                               float* __restrict__ alpha, int H, int n) {
  int idx = blockIdx.x * blockDim.x + threadIdx.x;
  if (idx >= n * H) return;
  int i = idx / H, hh = idx % H;
  float hdv = hd[idx];
  int p0 = offs[i], p1 = offs[i + 1];
  float m = -1e30f;
  for (int p = p0; p < p1; ++p) {
    float e = hs[csr_src[p] * H + hh] + hdv;
    e = e > 0.f ? e : 0.2f * e;
    alpha[(size_t)p * H + hh] = e;
    m = fmaxf(m, e);
  }
  float den = 0.f;
  for (int p = p0; p < p1; ++p) {
    float pe = __expf(alpha[(size_t)p * H + hh] - m);
    alpha[(size_t)p * H + hh] = pe;
    den += pe;
  }
  float inv = 1.f / (den + 1e-16f);
  for (int p = p0; p < p1; ++p) alpha[(size_t)p * H + hh] *= inv;
}

// ---------------------------------------------------------------- aggregation
template <int HC, int VPT, int TPB>
__global__ __launch_bounds__(TPB) void aggregate_kernel(
    const u16* __restrict__ h, const float* __restrict__ alpha,
    const int* __restrict__ csr_src, const int* __restrict__ offs,
    const void* __restrict__ bias, u16* __restrict__ outb, void* __restrict__ outv,
    int H, int C, int do_elu, const int* __restrict__ FLAG) {
  int isbf = *FLAG;
  int i = blockIdx.x;
  int t = threadIdx.x;
  int c0 = t * VPT;
  int head = c0 / C;
  float acc[VPT];
#pragma unroll
  for (int j = 0; j < VPT; j++) acc[j] = 0.f;
  int p0 = offs[i], p1 = offs[i + 1];
  for (int p = p0; p < p1; ++p) {
    int s = csr_src[p];
    float al = alpha[(size_t)p * H + head];
    const u16* hp = h + (size_t)s * HC + c0;
    if constexpr (VPT == 8) {
      u16x8 v = *(const u16x8*)hp;
#pragma unroll
      for (int j = 0; j < 8; j++) acc[j] += al * b2f(v[j]);
    } else if constexpr (VPT == 4) {
      u16x4 v = *(const u16x4*)hp;
#pragma unroll
      for (int j = 0; j < 4; j++) acc[j] += al * b2f(v[j]);
    } else {
      acc[0] += al * b2f(hp[0]);
    }
  }
  float r[VPT];
#pragma unroll
  for (int j = 0; j < VPT; j++) {
    r[j] = acc[j] + ldf(bias, c0 + j, isbf);
    if (do_elu) r[j] = r[j] > 0.f ? r[j] : expm1f(r[j]);
  }
  if (outb) {
    if constexpr (VPT == 8) {
      u16x8 o;
#pragma unroll
      for (int j = 0; j < 8; j++) o[j] = f2b(r[j]);
      *(u16x8*)(outb + (size_t)i * HC + c0) = o;
    } else if constexpr (VPT == 4) {
      u16x4 o;
#pragma unroll
      for (int j = 0; j < 4; j++) o[j] = f2b(r[j]);
      *(u16x4*)(outb + (size_t)i * HC + c0) = o;
    } else {
      outb[(size_t)i * HC + c0] = f2b(r[0]);
    }
  }
  if (outv) {
#pragma unroll
    for (int j = 0; j < VPT; j++)
      stf(outv, (size_t)10000 + (size_t)i * HC + c0 + j, isbf, r[j]);
  }
}

// ---------------------------------------------------------------- final dot (h2[128] . r3w + r3b)
__global__ __launch_bounds__(256) void dot128_kernel(const u16* __restrict__ h2,
                                                     const void* __restrict__ r3w,
                                                     const void* __restrict__ r3b,
                                                     void* __restrict__ scores,
                                                     const int* __restrict__ FLAG) {
  int isbf = *FLAG;
  int wid = threadIdx.x >> 6, lane = threadIdx.x & 63;
  int i = blockIdx.x * 4 + wid;
  if (i >= NN) return;
  const u16* hp = h2 + (size_t)i * 128;
  float v = b2f(hp[lane]) * ldf(r3w, lane, isbf) +
            b2f(hp[lane + 64]) * ldf(r3w, lane + 64, isbf);
  for (int o = 32; o; o >>= 1) v += __shfl_down(v, o);
  if (lane == 0) stf(scores, i, isbf, v + ldf(r3b, 0, isbf));
}

// ---------------------------------------------------------------- launch
extern "C" void kernel_launch(void* const* d_in, const int* in_sizes, int n_in,
                              void* d_out, int out_size, void* d_ws, size_t ws_size,
                              hipStream_t stream) {
  const void* x   = d_in[0];
  const int* ei   = (const int*)d_in[1];
  const void* W1  = d_in[2];
  const void* as1 = d_in[3];
  const void* ad1 = d_in[4];
  const void* b1  = d_in[5];
  const void* W2  = d_in[6];
  const void* as2 = d_in[7];
  const void* ad2 = d_in[8];
  const void* b2  = d_in[9];
  const void* W3  = d_in[10];
  const void* as3 = d_in[11];
  const void* ad3 = d_in[12];
  const void* b3  = d_in[13];
  const void* r1w = d_in[14];
  const void* r1b = d_in[15];
  const void* r2w = d_in[16];
  const void* r2b = d_in[17];
  const void* r3w = d_in[18];
  const void* r3b = d_in[19];

  char* ws = (char*)d_ws;
  size_t o = 0;
  auto alloc = [&](size_t bytes) { void* p = ws + o; o += (bytes + 255) & ~(size_t)255; return p; };
  u16* XC     = (u16*)alloc((size_t)NN * 768 * 2);
  u16* W1T    = (u16*)alloc((size_t)2048 * 768 * 2);
  u16* W2T    = (u16*)alloc((size_t)1024 * 2048 * 2);
  u16* W3T    = (u16*)alloc((size_t)64 * 1024 * 2);
  u16* R1T    = (u16*)alloc((size_t)256 * 64 * 2);
  u16* R2T    = (u16*)alloc((size_t)128 * 256 * 2);
  u16* Hbuf   = (u16*)alloc((size_t)NN * 2048 * 2);
  u16* Xbuf   = (u16*)alloc((size_t)NN * 2048 * 2);
  u16* X3B    = (u16*)alloc((size_t)NN * 64 * 2);
  u16* H1B    = (u16*)alloc((size_t)NN * 256 * 2);
  u16* H2B    = (u16*)alloc((size_t)NN * 128 * 2);
  float* HS   = (float*)alloc((size_t)NN * 8 * 4);
  float* HD   = (float*)alloc((size_t)NN * 8 * 4);
  int* DEG    = (int*)alloc((size_t)NN * 4);
  int* OFFS   = (int*)alloc((size_t)(NN + 1) * 4);
  int* CURSOR = (int*)alloc((size_t)NN * 4);
  int* CSR    = (int*)alloc((size_t)NTOT * 4);
  float* ALPHA = (float*)alloc((size_t)NTOT * 8 * 4);
  int* FLAG   = (int*)alloc(256);

  detect_kernel<<<1, 64, 0, stream>>>(x, FLAG);
  cvt_kernel<<<(NN * 768 + 255) / 256, 256, 0, stream>>>(x, XC, NN * 768, FLAG);

  transpose_kernel<<<dim3(2048 / 32, 768 / 32), dim3(32, 8), 0, stream>>>(W1, W1T, 768, 2048, FLAG);
  transpose_kernel<<<dim3(1024 / 32, 2048 / 32), dim3(32, 8), 0, stream>>>(W2, W2T, 2048, 1024, FLAG);
  transpose_kernel<<<dim3(64 / 32, 1024 / 32), dim3(32, 8), 0, stream>>>(W3, W3T, 1024, 64, FLAG);
  transpose_kernel<<<dim3(256 / 32, 64 / 32), dim3(32, 8), 0, stream>>>(r1w, R1T, 64, 256, FLAG);
  transpose_kernel<<<dim3(128 / 32, 256 / 32), dim3(32, 8), 0, stream>>>(r2w, R2T, 256, 128, FLAG);

  init_deg_kernel<<<(NN + 255) / 256, 256, 0, stream>>>(DEG);
  count_deg_kernel<<<(NE + 255) / 256, 256, 0, stream>>>(ei, DEG);
  scan_kernel<<<1, 1024, 0, stream>>>(DEG, OFFS, CURSOR, NN);
  scatter_kernel<<<(NTOT + 255) / 256, 256, 0, stream>>>(ei, CURSOR, CSR);

  const int MT = (NN + 127) / 128;   // 79
  const int MT64 = (NN + 63) / 64;   // 157

  // ---- layer 1: 768 -> 8 x 256
  gemm_kernel<128, 128, 2, 2><<<MT * 16, 256, 0, stream>>>(XC, W1T, Hbuf, NN, 768, 2048, 16, nullptr, 0, FLAG);
  dot_av_kernel<<<(NN * 8 + 3) / 4, 256, 0, stream>>>(Hbuf, as1, ad1, HS, HD, 8, 256, NN, FLAG);
  softmax_kernel<<<(NN * 8 + 255) / 256, 256, 0, stream>>>(CSR, OFFS, HS, HD, ALPHA, 8, NN);
  aggregate_kernel<2048, 8, 256><<<NN, 256, 0, stream>>>(Hbuf, ALPHA, CSR, OFFS, b1, Xbuf, nullptr, 8, 256, 1, FLAG);

  // ---- layer 2: 2048 -> 4 x 256 (64x128 tile: 1256 blocks ~= 5/CU)
  gemm_kernel<64, 128, 2, 2><<<MT64 * 8, 256, 0, stream>>>(Xbuf, W2T, Hbuf, NN, 2048, 1024, 8, nullptr, 0, FLAG);
  dot_av_kernel<<<(NN * 4 + 3) / 4, 256, 0, stream>>>(Hbuf, as2, ad2, HS, HD, 4, 256, NN, FLAG);
  softmax_kernel<<<(NN * 4 + 255) / 256, 256, 0, stream>>>(CSR, OFFS, HS, HD, ALPHA, 4, NN);
  aggregate_kernel<1024, 4, 256><<<NN, 256, 0, stream>>>(Hbuf, ALPHA, CSR, OFFS, b2, Xbuf, nullptr, 4, 256, 1, FLAG);

  // ---- layer 3: 1024 -> 1 x 64
  gemm_kernel<128, 64, 4, 1><<<MT, 256, 0, stream>>>(Xbuf, W3T, Hbuf, NN, 1024, 64, 1, nullptr, 0, FLAG);
  dot_av_kernel<<<(NN + 3) / 4, 256, 0, stream>>>(Hbuf, as3, ad3, HS, HD, 1, 64, NN, FLAG);
  softmax_kernel<<<(NN + 255) / 256, 256, 0, stream>>>(CSR, OFFS, HS, HD, ALPHA, 1, NN);
  aggregate_kernel<64, 1, 64><<<NN, 64, 0, stream>>>(Hbuf, ALPHA, CSR, OFFS, b3, X3B, d_out, 1, 64, 0, FLAG);

  // ---- reasoning MLP as MFMA GEMMs + final dot
  gemm_kernel<64, 64, 2, 2><<<MT64 * 4, 256, 0, stream>>>(X3B, R1T, H1B, NN, 64, 256, 4, r1b, 1, FLAG);
  gemm_kernel<64, 64, 2, 2><<<MT64 * 2, 256, 0, stream>>>(H1B, R2T, H2B, NN, 256, 128, 2, r2b, 1, FLAG);
  dot128_kernel<<<(NN + 3) / 4, 256, 0, stream>>>(H2B, r3w, r3b, d_out, FLAG);
}

// Round 7
// 424.850 us; speedup vs baseline: 1.8973x; 1.0670x over previous
//
#include <hip/hip_runtime.h>
#include <stdint.h>

typedef unsigned short u16;
using s16x8 = __attribute__((ext_vector_type(8))) short;
using f32x4 = __attribute__((ext_vector_type(4))) float;
using u16x8 = __attribute__((ext_vector_type(8))) unsigned short;
using u16x4 = __attribute__((ext_vector_type(4))) unsigned short;

#define DEVINL __device__ __forceinline__

DEVINL float b2f(u16 u) { return __uint_as_float(((uint32_t)u) << 16); }
DEVINL u16 f2b(float f) {
  uint32_t x = __float_as_uint(f);
  return (u16)((x + 0x7fffu + ((x >> 16) & 1u)) >> 16);
}
// dtype-agnostic load/store: isbf=1 -> bf16 (u16), else fp32
DEVINL float ldf(const void* p, size_t i, int isbf) {
  return isbf ? b2f(((const u16*)p)[i]) : ((const float*)p)[i];
}
DEVINL void stf(void* p, size_t i, int isbf, float v) {
  if (isbf) ((u16*)p)[i] = f2b(v);
  else      ((float*)p)[i] = v;
}

typedef __attribute__((address_space(1))) const void gvoid;
typedef __attribute__((address_space(3))) void lvoid;
DEVINL void gload_lds16(const u16* g, u16* l) {
  __builtin_amdgcn_global_load_lds((gvoid*)g, (lvoid*)l, 16, 0, 0);
}

constexpr int NN = 10000;     // nodes
constexpr int NE = 80000;     // edges (no self loops)
constexpr int NTOT = 90000;   // edges + self loops

// ---------------------------------------------------------------- dtype detect
__global__ void detect_kernel(const void* __restrict__ x, int* __restrict__ flag) {
  int lane = threadIdx.x;  // 64
  u16 w = ((const u16*)x)[lane * 97 + 13];
  int e = (w >> 7) & 0xFF;
  int sane = (e >= 0x50 && e <= 0x8A) ? 1 : 0;
  unsigned long long b = __ballot(sane);
  if (lane == 0) flag[0] = (__popcll(b) >= 56) ? 1 : 0;
}

// canonicalize x -> bf16
__global__ void cvt_kernel(const void* __restrict__ in, u16* __restrict__ out,
                           int n, const int* __restrict__ FLAG) {
  int isbf = *FLAG;
  int i = blockIdx.x * 256 + threadIdx.x;
  if (i >= n) return;
  out[i] = isbf ? ((const u16*)in)[i] : f2b(((const float*)in)[i]);
}

// ---------------------------------------------------------------- batched transpose
struct TD { const void* in; u16* out; int R, C, t0; };
struct TD5 { TD d[5]; };
__global__ void transpose_all(TD5 td, const int* __restrict__ FLAG) {
  int isbf = *FLAG;
  __shared__ float tile[32][33];
  int t = blockIdx.x;
  int k = 0;
#pragma unroll
  for (int j = 1; j < 5; j++) if (t >= td.d[j].t0) k = j;
  const void* in = td.d[k].in;
  u16* out = td.d[k].out;
  int R = td.d[k].R, C = td.d[k].C;
  int tl = t - td.d[k].t0;
  int tcols = C / 32;
  int bx = (tl % tcols) * 32, by = (tl / tcols) * 32;
  int tx = threadIdx.x, ty = threadIdx.y;  // (32,8)
  for (int j = 0; j < 32; j += 8) {
    int r = by + ty + j, c = bx + tx;
    tile[ty + j][tx] = ldf(in, (size_t)r * C + c, isbf);
  }
  __syncthreads();
  for (int j = 0; j < 32; j += 8) {
    int r = bx + ty + j, c = by + tx;
    out[(size_t)r * R + c] = f2b(tile[tx][ty + j]);
  }
}

// ---------------------------------------------------------------- CSR build + zero HS/HD
__global__ void init_kernel(int* __restrict__ deg, float* __restrict__ hz, int nz) {
  int i = blockIdx.x * blockDim.x + threadIdx.x;
  if (i < NN) deg[i] = 1;  // self loop
  if (i < nz) hz[i] = 0.f;
}

__global__ void count_deg_kernel(const int* __restrict__ ei, int* __restrict__ deg) {
  int e = blockIdx.x * blockDim.x + threadIdx.x;
  if (e < NE) atomicAdd(&deg[ei[NE + e]], 1);
}

__global__ __launch_bounds__(1024) void scan_kernel(const int* __restrict__ deg,
                                                    int* __restrict__ offs,
                                                    int* __restrict__ cursor, int n) {
  __shared__ int wsum[16];
  __shared__ int carry_s;
  int tid = threadIdx.x, lane = tid & 63, wid = tid >> 6;
  if (tid == 0) carry_s = 0;
  __syncthreads();
  for (int base = 0; base < n; base += 1024) {
    int idx = base + tid;
    int v = (idx < n) ? deg[idx] : 0;
    int s = v;
#pragma unroll
    for (int o = 1; o < 64; o <<= 1) { int t = __shfl_up(s, o); if (lane >= o) s += t; }
    if (lane == 63) wsum[wid] = s;
    __syncthreads();
    if (wid == 0) {
      int w = (lane < 16) ? wsum[lane] : 0;
#pragma unroll
      for (int o = 1; o < 16; o <<= 1) { int t = __shfl_up(w, o); if (lane >= o) w += t; }
      if (lane < 16) wsum[lane] = w;
    }
    __syncthreads();
    int inc = s + (wid > 0 ? wsum[wid - 1] : 0) + carry_s;
    if (idx < n) { offs[idx + 1] = inc; cursor[idx] = inc - v; }
    __syncthreads();
    if (tid == 0) carry_s += wsum[15];
    __syncthreads();
  }
  if (tid == 0) offs[0] = 0;
}

__global__ void scatter_kernel(const int* __restrict__ ei, int* __restrict__ cursor,
                               int* __restrict__ csr_src) {
  int e = blockIdx.x * blockDim.x + threadIdx.x;
  if (e >= NTOT) return;
  int s, d;
  if (e < NE) { s = ei[e]; d = ei[NE + e]; }
  else        { s = e - NE; d = s; }
  int pos = atomicAdd(&cursor[d], 1);
  csr_src[pos] = s;
}

// ---------------------------------------------------------------- GEMM (bf16 MFMA)
// C[M,N] = A[M,K] * Bt[N,K]^T. m97 structure + both-sides swizzle + XCD remap
// + LDS-staged coalesced C store + optional fused {bias,relu} and fused
// attention dots (hs/hd partial sums via 16-lane reduce + atomicAdd).
template <int BM, int BN, int WM, int WN>
__global__ __launch_bounds__(256) void gemm_kernel(const u16* __restrict__ A,
                                                   const u16* __restrict__ Bt,
                                                   u16* __restrict__ C,
                                                   int M, int K, int N, int nN,
                                                   const void* __restrict__ bias,
                                                   int do_relu,
                                                   const void* __restrict__ asrc,
                                                   const void* __restrict__ adst,
                                                   float* __restrict__ hs,
                                                   float* __restrict__ hd,
                                                   int H, int Cc,
                                                   const int* __restrict__ FLAG) {
  constexpr int BK = 64;             // 128 B per LDS row
  constexpr int WTM = BM / WM, WTN = BN / WN;
  constexpr int FM = WTM / 16, FN = WTN / 16;
  constexpr int ACH = BM / 32;       // 1KB staging chunks per wave (A)
  constexpr int BCH = BN / 32;

  __shared__ u16 smem[(BM + BN) * BK];
  u16* lA = smem;
  u16* lB = smem + BM * BK;

  int tid = threadIdx.x;
  int lane = tid & 63, wid = tid >> 6;
  int wm = wid / WN, wn = wid % WN;
  int isbf = (bias || asrc) ? *FLAG : 0;

  // bijective XCD remap (m204)
  int nwg = gridDim.x;
  int q = nwg >> 3, r = nwg & 7;
  int xcd = blockIdx.x & 7, pos = blockIdx.x >> 3;
  int wgid = (xcd < r ? xcd * (q + 1) : r * (q + 1) + (xcd - r) * q) + pos;
  int bm0 = (wgid / nN) * BM, bn0 = (wgid % nN) * BN;

  int srow = lane >> 3;                               // row within 8-row chunk
  int scol = ((lane & 7) ^ (lane >> 3)) << 3;         // SWIZZLED source col (u16)

  f32x4 acc[FM][FN];
#pragma unroll
  for (int m = 0; m < FM; m++)
#pragma unroll
    for (int n = 0; n < FN; n++) acc[m][n] = (f32x4){0.f, 0.f, 0.f, 0.f};

  for (int k0 = 0; k0 < K; k0 += BK) {
    // ---- stage tile: linear LDS dest + swizzled global source (rule #21)
#pragma unroll
    for (int i = 0; i < ACH; i++) {
      int c = wid * ACH + i;
      int row = c * 8 + srow;
      int grow = bm0 + row;
      if (grow > M - 1) grow = M - 1;
      gload_lds16(A + (size_t)grow * K + k0 + scol, lA + c * 512);
    }
#pragma unroll
    for (int i = 0; i < BCH; i++) {
      int c = wid * BCH + i;
      int row = c * 8 + srow;
      gload_lds16(Bt + (size_t)(bn0 + row) * K + k0 + scol, lB + c * 512);
    }
    __syncthreads();  // drains vmcnt(0) -> LDS tile ready

    // ---- MFMA over BK (2 x k=32 steps), swizzled reads
    int swz = (lane & 7) << 4;
#pragma unroll
    for (int ks = 0; ks < 2; ks++) {
      int kb = ks * 64 + ((lane >> 4) << 4);  // linear byte offset in 128B row
      s16x8 af[FM], bf[FN];
#pragma unroll
      for (int m = 0; m < FM; m++) {
        int row = wm * WTM + m * 16 + (lane & 15);
        af[m] = *(const s16x8*)((const char*)lA + row * 128 + (kb ^ swz));
      }
#pragma unroll
      for (int n = 0; n < FN; n++) {
        int row = wn * WTN + n * 16 + (lane & 15);
        bf[n] = *(const s16x8*)((const char*)lB + row * 128 + (kb ^ swz));
      }
#pragma unroll
      for (int m = 0; m < FM; m++)
#pragma unroll
        for (int n = 0; n < FN; n++)
          acc[m][n] = __builtin_amdgcn_mfma_f32_16x16x32_bf16(af[m], bf[n], acc[m][n], 0, 0, 0);
    }
    __syncthreads();  // LDS consumed; safe to restage
  }

  // ---- epilogue: bias/relu, optional fused hs/hd dots, LDS-staged C store
  u16* lC = smem;  // BM*BN u16 <= (BM+BN)*BK for our configs
  int r0 = (lane >> 4) * 4;
  int head = hs ? (bn0 / Cc) : 0;
  float asv[FN], adv[FN];
  float sa[FM][4], da[FM][4];
  if (hs) {
#pragma unroll
    for (int n = 0; n < FN; n++) {
      int colC = (bn0 % Cc) + wn * WTN + n * 16 + (lane & 15);
      asv[n] = ldf(asrc, (size_t)head * Cc + colC, isbf);
      adv[n] = ldf(adst, (size_t)head * Cc + colC, isbf);
    }
#pragma unroll
    for (int m = 0; m < FM; m++)
#pragma unroll
      for (int rr = 0; rr < 4; rr++) { sa[m][rr] = 0.f; da[m][rr] = 0.f; }
  }
#pragma unroll
  for (int m = 0; m < FM; m++)
#pragma unroll
    for (int n = 0; n < FN; n++)
#pragma unroll
      for (int rr = 0; rr < 4; rr++) {
        int row = wm * WTM + m * 16 + r0 + rr;
        int col = wn * WTN + n * 16 + (lane & 15);
        float v = acc[m][n][rr];
        if (bias) v += ldf(bias, bn0 + col, isbf);
        if (do_relu) v = fmaxf(v, 0.f);
        if (hs) { sa[m][rr] += v * asv[n]; da[m][rr] += v * adv[n]; }
        lC[row * BN + col] = f2b(v);
      }
  if (hs) {
#pragma unroll
    for (int m = 0; m < FM; m++) {
#pragma unroll
      for (int mask = 1; mask < 16; mask <<= 1)
#pragma unroll
        for (int rr = 0; rr < 4; rr++) {
          sa[m][rr] += __shfl_xor(sa[m][rr], mask);
          da[m][rr] += __shfl_xor(da[m][rr], mask);
        }
      if ((lane & 15) == 0) {
#pragma unroll
        for (int rr = 0; rr < 4; rr++) {
          int grow = bm0 + wm * WTM + m * 16 + r0 + rr;
          if (grow < M) {
            atomicAdd(&hs[(size_t)grow * H + head], sa[m][rr]);
            atomicAdd(&hd[(size_t)grow * H + head], da[m][rr]);
          }
        }
      }
    }
  }
  __syncthreads();
  constexpr int CHUNKS = BM * BN / 2048;  // 16B chunks per thread
  constexpr int CPR = BN / 8;             // chunks per C row
#pragma unroll
  for (int j = 0; j < CHUNKS; j++) {
    int idx = j * 256 + tid;
    int row = idx / CPR, colb = (idx % CPR) * 16;
    int grow = bm0 + row;
    if (grow < M) {
      int4 v = *(const int4*)((const char*)lC + idx * 16);
      *(int4*)((char*)C + ((size_t)grow * N + bn0) * 2 + colb) = v;
    }
  }
}

// ---------------------------------------------------------------- edge softmax
__global__ void softmax_kernel(const int* __restrict__ csr_src, const int* __restrict__ offs,
                               const float* __restrict__ hs, const float* __restrict__ hd,
                               float* __restrict__ alpha, int H, int n) {
  int idx = blockIdx.x * blockDim.x + threadIdx.x;
  if (idx >= n * H) return;
  int i = idx / H, hh = idx % H;
  float hdv = hd[idx];
  int p0 = offs[i], p1 = offs[i + 1];
  float m = -1e30f;
  for (int p = p0; p < p1; ++p) {
    float e = hs[csr_src[p] * H + hh] + hdv;
    e = e > 0.f ? e : 0.2f * e;
    alpha[(size_t)p * H + hh] = e;
    m = fmaxf(m, e);
  }
  float den = 0.f;
  for (int p = p0; p < p1; ++p) {
    float pe = __expf(alpha[(size_t)p * H + hh] - m);
    alpha[(size_t)p * H + hh] = pe;
    den += pe;
  }
  float inv = 1.f / (den + 1e-16f);
  for (int p = p0; p < p1; ++p) alpha[(size_t)p * H + hh] *= inv;
}

// ---------------------------------------------------------------- aggregation
template <int HC, int VPT, int TPB>
__global__ __launch_bounds__(TPB) void aggregate_kernel(
    const u16* __restrict__ h, const float* __restrict__ alpha,
    const int* __restrict__ csr_src, const int* __restrict__ offs,
    const void* __restrict__ bias, u16* __restrict__ outb, void* __restrict__ outv,
    int H, int C, int do_elu, const int* __restrict__ FLAG) {
  int isbf = *FLAG;
  int i = blockIdx.x;
  int t = threadIdx.x;
  int c0 = t * VPT;
  int head = c0 / C;
  float acc[VPT];
#pragma unroll
  for (int j = 0; j < VPT; j++) acc[j] = 0.f;
  int p0 = offs[i], p1 = offs[i + 1];
  int p = p0;
  for (; p + 2 <= p1; p += 2) {  // unroll x2: two row reads in flight
    int s0 = csr_src[p], s1 = csr_src[p + 1];
    float a0 = alpha[(size_t)p * H + head];
    float a1 = alpha[(size_t)(p + 1) * H + head];
    const u16* h0 = h + (size_t)s0 * HC + c0;
    const u16* h1 = h + (size_t)s1 * HC + c0;
    if constexpr (VPT == 8) {
      u16x8 v0 = *(const u16x8*)h0, v1 = *(const u16x8*)h1;
#pragma unroll
      for (int j = 0; j < 8; j++) acc[j] += a0 * b2f(v0[j]) + a1 * b2f(v1[j]);
    } else if constexpr (VPT == 4) {
      u16x4 v0 = *(const u16x4*)h0, v1 = *(const u16x4*)h1;
#pragma unroll
      for (int j = 0; j < 4; j++) acc[j] += a0 * b2f(v0[j]) + a1 * b2f(v1[j]);
    } else {
      acc[0] += a0 * b2f(h0[0]) + a1 * b2f(h1[0]);
    }
  }
  if (p < p1) {
    int s0 = csr_src[p];
    float a0 = alpha[(size_t)p * H + head];
    const u16* h0 = h + (size_t)s0 * HC + c0;
    if constexpr (VPT == 8) {
      u16x8 v0 = *(const u16x8*)h0;
#pragma unroll
      for (int j = 0; j < 8; j++) acc[j] += a0 * b2f(v0[j]);
    } else if constexpr (VPT == 4) {
      u16x4 v0 = *(const u16x4*)h0;
#pragma unroll
      for (int j = 0; j < 4; j++) acc[j] += a0 * b2f(v0[j]);
    } else {
      acc[0] += a0 * b2f(h0[0]);
    }
  }
  float r[VPT];
#pragma unroll
  for (int j = 0; j < VPT; j++) {
    r[j] = acc[j] + ldf(bias, c0 + j, isbf);
    if (do_elu) r[j] = r[j] > 0.f ? r[j] : expm1f(r[j]);
  }
  if (outb) {
    if constexpr (VPT == 8) {
      u16x8 o;
#pragma unroll
      for (int j = 0; j < 8; j++) o[j] = f2b(r[j]);
      *(u16x8*)(outb + (size_t)i * HC + c0) = o;
    } else if constexpr (VPT == 4) {
      u16x4 o;
#pragma unroll
      for (int j = 0; j < 4; j++) o[j] = f2b(r[j]);
      *(u16x4*)(outb + (size_t)i * HC + c0) = o;
    } else {
      outb[(size_t)i * HC + c0] = f2b(r[0]);
    }
  }
  if (outv) {
#pragma unroll
    for (int j = 0; j < VPT; j++)
      stf(outv, (size_t)10000 + (size_t)i * HC + c0 + j, isbf, r[j]);
  }
}

// ---------------------------------------------------------------- final dot (h2[128] . r3w + r3b)
__global__ __launch_bounds__(256) void dot128_kernel(const u16* __restrict__ h2,
                                                     const void* __restrict__ r3w,
                                                     const void* __restrict__ r3b,
                                                     void* __restrict__ scores,
                                                     const int* __restrict__ FLAG) {
  int isbf = *FLAG;
  int wid = threadIdx.x >> 6, lane = threadIdx.x & 63;
  int i = blockIdx.x * 4 + wid;
  if (i >= NN) return;
  const u16* hp = h2 + (size_t)i * 128;
  float v = b2f(hp[lane]) * ldf(r3w, lane, isbf) +
            b2f(hp[lane + 64]) * ldf(r3w, lane + 64, isbf);
  for (int o = 32; o; o >>= 1) v += __shfl_down(v, o);
  if (lane == 0) stf(scores, i, isbf, v + ldf(r3b, 0, isbf));
}

// ---------------------------------------------------------------- launch
extern "C" void kernel_launch(void* const* d_in, const int* in_sizes, int n_in,
                              void* d_out, int out_size, void* d_ws, size_t ws_size,
                              hipStream_t stream) {
  const void* x   = d_in[0];
  const int* ei   = (const int*)d_in[1];
  const void* W1  = d_in[2];
  const void* as1 = d_in[3];
  const void* ad1 = d_in[4];
  const void* b1  = d_in[5];
  const void* W2  = d_in[6];
  const void* as2 = d_in[7];
  const void* ad2 = d_in[8];
  const void* b2  = d_in[9];
  const void* W3  = d_in[10];
  const void* as3 = d_in[11];
  const void* ad3 = d_in[12];
  const void* b3  = d_in[13];
  const void* r1w = d_in[14];
  const void* r1b = d_in[15];
  const void* r2w = d_in[16];
  const void* r2b = d_in[17];
  const void* r3w = d_in[18];
  const void* r3b = d_in[19];

  char* ws = (char*)d_ws;
  size_t o = 0;
  auto alloc = [&](size_t bytes) { void* p = ws + o; o += (bytes + 255) & ~(size_t)255; return p; };
  u16* XC     = (u16*)alloc((size_t)NN * 768 * 2);
  u16* W1T    = (u16*)alloc((size_t)2048 * 768 * 2);
  u16* W2T    = (u16*)alloc((size_t)1024 * 2048 * 2);
  u16* W3T    = (u16*)alloc((size_t)64 * 1024 * 2);
  u16* R1T    = (u16*)alloc((size_t)256 * 64 * 2);
  u16* R2T    = (u16*)alloc((size_t)128 * 256 * 2);
  u16* Hbuf   = (u16*)alloc((size_t)NN * 2048 * 2);
  u16* Xbuf   = (u16*)alloc((size_t)NN * 2048 * 2);
  u16* X3B    = (u16*)alloc((size_t)NN * 64 * 2);
  u16* H1B    = (u16*)alloc((size_t)NN * 256 * 2);
  u16* H2B    = (u16*)alloc((size_t)NN * 128 * 2);
  float* HZ   = (float*)alloc((size_t)NN * 26 * 4);  // HS1 HD1 HS2 HD2 HS3 HD3
  float* HS1  = HZ;
  float* HD1  = HZ + (size_t)NN * 8;
  float* HS2  = HZ + (size_t)NN * 16;
  float* HD2  = HZ + (size_t)NN * 20;
  float* HS3  = HZ + (size_t)NN * 24;
  float* HD3  = HZ + (size_t)NN * 25;
  int* DEG    = (int*)alloc((size_t)NN * 4);
  int* OFFS   = (int*)alloc((size_t)(NN + 1) * 4);
  int* CURSOR = (int*)alloc((size_t)NN * 4);
  int* CSR    = (int*)alloc((size_t)NTOT * 4);
  float* ALPHA = (float*)alloc((size_t)NTOT * 8 * 4);
  int* FLAG   = (int*)alloc(256);

  detect_kernel<<<1, 64, 0, stream>>>(x, FLAG);
  cvt_kernel<<<(NN * 768 + 255) / 256, 256, 0, stream>>>(x, XC, NN * 768, FLAG);

  // batched weight transposes
  TD5 td;
  td.d[0] = {W1,  W1T, 768, 2048, 0};
  td.d[1] = {W2,  W2T, 2048, 1024, 0};
  td.d[2] = {W3,  W3T, 1024, 64, 0};
  td.d[3] = {r1w, R1T, 64, 256, 0};
  td.d[4] = {r2w, R2T, 256, 128, 0};
  int cum = 0;
  for (int k = 0; k < 5; k++) {
    td.d[k].t0 = cum;
    cum += (td.d[k].R / 32) * (td.d[k].C / 32);
  }
  transpose_all<<<cum, dim3(32, 8), 0, stream>>>(td, FLAG);

  init_kernel<<<(NN * 26 + 255) / 256, 256, 0, stream>>>(DEG, HZ, NN * 26);
  count_deg_kernel<<<(NE + 255) / 256, 256, 0, stream>>>(ei, DEG);
  scan_kernel<<<1, 1024, 0, stream>>>(DEG, OFFS, CURSOR, NN);
  scatter_kernel<<<(NTOT + 255) / 256, 256, 0, stream>>>(ei, CURSOR, CSR);

  const int MT = (NN + 127) / 128;   // 79
  const int MT64 = (NN + 63) / 64;   // 157

  // ---- layer 1: 768 -> 8 x 256 (fused hs/hd dots)
  gemm_kernel<128, 128, 2, 2><<<MT * 16, 256, 0, stream>>>(
      XC, W1T, Hbuf, NN, 768, 2048, 16, nullptr, 0, as1, ad1, HS1, HD1, 8, 256, FLAG);
  softmax_kernel<<<(NN * 8 + 255) / 256, 256, 0, stream>>>(CSR, OFFS, HS1, HD1, ALPHA, 8, NN);
  aggregate_kernel<2048, 8, 256><<<NN, 256, 0, stream>>>(Hbuf, ALPHA, CSR, OFFS, b1, Xbuf, nullptr, 8, 256, 1, FLAG);

  // ---- layer 2: 2048 -> 4 x 256
  gemm_kernel<64, 128, 2, 2><<<MT64 * 8, 256, 0, stream>>>(
      Xbuf, W2T, Hbuf, NN, 2048, 1024, 8, nullptr, 0, as2, ad2, HS2, HD2, 4, 256, FLAG);
  softmax_kernel<<<(NN * 4 + 255) / 256, 256, 0, stream>>>(CSR, OFFS, HS2, HD2, ALPHA, 4, NN);
  aggregate_kernel<1024, 4, 256><<<NN, 256, 0, stream>>>(Hbuf, ALPHA, CSR, OFFS, b2, Xbuf, nullptr, 4, 256, 1, FLAG);

  // ---- layer 3: 1024 -> 1 x 64
  gemm_kernel<128, 64, 4, 1><<<MT, 256, 0, stream>>>(
      Xbuf, W3T, Hbuf, NN, 1024, 64, 1, nullptr, 0, as3, ad3, HS3, HD3, 1, 64, FLAG);
  softmax_kernel<<<(NN + 255) / 256, 256, 0, stream>>>(CSR, OFFS, HS3, HD3, ALPHA, 1, NN);
  aggregate_kernel<64, 1, 64><<<NN, 64, 0, stream>>>(Hbuf, ALPHA, CSR, OFFS, b3, X3B, d_out, 1, 64, 0, FLAG);

  // ---- reasoning MLP as MFMA GEMMs + final dot
  gemm_kernel<64, 64, 2, 2><<<MT64 * 4, 256, 0, stream>>>(
      X3B, R1T, H1B, NN, 64, 256, 4, r1b, 1, nullptr, nullptr, nullptr, nullptr, 0, 0, FLAG);
  gemm_kernel<64, 64, 2, 2><<<MT64 * 2, 256, 0, stream>>>(
      H1B, R2T, H2B, NN, 256, 128, 2, r2b, 1, nullptr, nullptr, nullptr, nullptr, 0, 0, FLAG);
  dot128_kernel<<<(NN + 3) / 4, 256, 0, stream>>>(H2B, r3w, r3b, d_out, FLAG);
}

// Round 9
// 376.198 us; speedup vs baseline: 2.1426x; 1.1293x over previous
//
#include <hip/hip_runtime.h>
#include <stdint.h>

typedef unsigned short u16;
using s16x8 = __attribute__((ext_vector_type(8))) short;
using f32x4 = __attribute__((ext_vector_type(4))) float;
using u16x8 = __attribute__((ext_vector_type(8))) unsigned short;
using u16x4 = __attribute__((ext_vector_type(4))) unsigned short;

#define DEVINL __device__ __forceinline__

DEVINL float b2f(u16 u) { return __uint_as_float(((uint32_t)u) << 16); }
DEVINL u16 f2b(float f) {
  uint32_t x = __float_as_uint(f);
  return (u16)((x + 0x7fffu + ((x >> 16) & 1u)) >> 16);
}
// dtype-agnostic load/store: isbf=1 -> bf16 (u16), else fp32
DEVINL float ldf(const void* p, size_t i, int isbf) {
  return isbf ? b2f(((const u16*)p)[i]) : ((const float*)p)[i];
}
DEVINL void stf(void* p, size_t i, int isbf, float v) {
  if (isbf) ((u16*)p)[i] = f2b(v);
  else      ((float*)p)[i] = v;
}

typedef __attribute__((address_space(1))) const void gvoid;
typedef __attribute__((address_space(3))) void lvoid;
DEVINL void gload_lds16(const u16* g, u16* l) {
  __builtin_amdgcn_global_load_lds((gvoid*)g, (lvoid*)l, 16, 0, 0);
}

constexpr int NN = 10000;     // nodes
constexpr int NE = 80000;     // edges (no self loops)
constexpr int NTOT = 90000;   // edges + self loops

// ---------------------------------------------------------------- dtype detect
__global__ void detect_kernel(const void* __restrict__ x, int* __restrict__ flag) {
  int lane = threadIdx.x;  // 64
  u16 w = ((const u16*)x)[lane * 97 + 13];
  int e = (w >> 7) & 0xFF;
  int sane = (e >= 0x50 && e <= 0x8A) ? 1 : 0;
  unsigned long long b = __ballot(sane);
  if (lane == 0) flag[0] = (__popcll(b) >= 56) ? 1 : 0;
}

// canonicalize x -> bf16
__global__ void cvt_kernel(const void* __restrict__ in, u16* __restrict__ out,
                           int n, const int* __restrict__ FLAG) {
  int isbf = *FLAG;
  int i = blockIdx.x * 256 + threadIdx.x;
  if (i >= n) return;
  out[i] = isbf ? ((const u16*)in)[i] : f2b(((const float*)in)[i]);
}

// ---------------------------------------------------------------- batched transpose
struct TD { const void* in; u16* out; int R, C, t0; };
struct TD5 { TD d[5]; };
__global__ void transpose_all(TD5 td, const int* __restrict__ FLAG) {
  int isbf = *FLAG;
  __shared__ float tile[32][33];
  int t = blockIdx.x;
  int k = 0;
#pragma unroll
  for (int j = 1; j < 5; j++) if (t >= td.d[j].t0) k = j;
  const void* in = td.d[k].in;
  u16* out = td.d[k].out;
  int R = td.d[k].R, C = td.d[k].C;
  int tl = t - td.d[k].t0;
  int tcols = C / 32;
  int bx = (tl % tcols) * 32, by = (tl / tcols) * 32;
  int tx = threadIdx.x, ty = threadIdx.y;  // (32,8)
  for (int j = 0; j < 32; j += 8) {
    int r = by + ty + j, c = bx + tx;
    tile[ty + j][tx] = ldf(in, (size_t)r * C + c, isbf);
  }
  __syncthreads();
  for (int j = 0; j < 32; j += 8) {
    int r = bx + ty + j, c = by + tx;
    out[(size_t)r * R + c] = f2b(tile[tx][ty + j]);
  }
}

// ---------------------------------------------------------------- CSR build + zero HS/HD
__global__ void init_kernel(int* __restrict__ deg, float* __restrict__ hz, int nz) {
  int i = blockIdx.x * blockDim.x + threadIdx.x;
  if (i < NN) deg[i] = 1;  // self loop
  if (i < nz) hz[i] = 0.f;
}

__global__ void count_deg_kernel(const int* __restrict__ ei, int* __restrict__ deg) {
  int e = blockIdx.x * blockDim.x + threadIdx.x;
  if (e < NE) atomicAdd(&deg[ei[NE + e]], 1);
}

__global__ __launch_bounds__(1024) void scan_kernel(const int* __restrict__ deg,
                                                    int* __restrict__ offs,
                                                    int* __restrict__ cursor, int n) {
  __shared__ int wsum[16];
  __shared__ int carry_s;
  int tid = threadIdx.x, lane = tid & 63, wid = tid >> 6;
  if (tid == 0) carry_s = 0;
  __syncthreads();
  for (int base = 0; base < n; base += 1024) {
    int idx = base + tid;
    int v = (idx < n) ? deg[idx] : 0;
    int s = v;
#pragma unroll
    for (int o = 1; o < 64; o <<= 1) { int t = __shfl_up(s, o); if (lane >= o) s += t; }
    if (lane == 63) wsum[wid] = s;
    __syncthreads();
    if (wid == 0) {
      int w = (lane < 16) ? wsum[lane] : 0;
#pragma unroll
      for (int o = 1; o < 16; o <<= 1) { int t = __shfl_up(w, o); if (lane >= o) w += t; }
      if (lane < 16) wsum[lane] = w;
    }
    __syncthreads();
    int inc = s + (wid > 0 ? wsum[wid - 1] : 0) + carry_s;
    if (idx < n) { offs[idx + 1] = inc; cursor[idx] = inc - v; }
    __syncthreads();
    if (tid == 0) carry_s += wsum[15];
    __syncthreads();
  }
  if (tid == 0) offs[0] = 0;
}

__global__ void scatter_kernel(const int* __restrict__ ei, int* __restrict__ cursor,
                               int* __restrict__ csr_src) {
  int e = blockIdx.x * blockDim.x + threadIdx.x;
  if (e >= NTOT) return;
  int s, d;
  if (e < NE) { s = ei[e]; d = ei[NE + e]; }
  else        { s = e - NE; d = s; }
  int pos = atomicAdd(&cursor[d], 1);
  csr_src[pos] = s;
}

// ---------------------------------------------------------------- GEMM (bf16 MFMA)
// C[M,N] = A[M,K] * Bt[N,K]^T. m97 structure + both-sides swizzle + XCD remap
// + LDS-staged coalesced C store + optional fused {bias,relu} and fused
// attention dots. hs/hd partials are WAVE-UNIQUE (race fix, round 8):
// part = (bn0 % Cc)/WTN + wn  in [0,4) -- each covers one 64-col slice.
// Stored at hs[(row*H+head)*4 + part]; softmax sums the float4.
template <int BM, int BN, int WM, int WN>
__global__ __launch_bounds__(256) void gemm_kernel(const u16* __restrict__ A,
                                                   const u16* __restrict__ Bt,
                                                   u16* __restrict__ C,
                                                   int M, int K, int N, int nN,
                                                   const void* __restrict__ bias,
                                                   int do_relu,
                                                   const void* __restrict__ asrc,
                                                   const void* __restrict__ adst,
                                                   float* __restrict__ hs,
                                                   float* __restrict__ hd,
                                                   int H, int Cc,
                                                   const int* __restrict__ FLAG) {
  constexpr int BK = 64;             // 128 B per LDS row
  constexpr int WTM = BM / WM, WTN = BN / WN;
  constexpr int FM = WTM / 16, FN = WTN / 16;
  constexpr int ACH = BM / 32;       // 1KB staging chunks per wave (A)
  constexpr int BCH = BN / 32;

  __shared__ u16 smem[(BM + BN) * BK];
  u16* lA = smem;
  u16* lB = smem + BM * BK;

  int tid = threadIdx.x;
  int lane = tid & 63, wid = tid >> 6;
  int wm = wid / WN, wn = wid % WN;
  int isbf = (bias || asrc) ? *FLAG : 0;

  // bijective XCD remap (m204)
  int nwg = gridDim.x;
  int q = nwg >> 3, r = nwg & 7;
  int xcd = blockIdx.x & 7, pos = blockIdx.x >> 3;
  int wgid = (xcd < r ? xcd * (q + 1) : r * (q + 1) + (xcd - r) * q) + pos;
  int bm0 = (wgid / nN) * BM, bn0 = (wgid % nN) * BN;

  int srow = lane >> 3;                               // row within 8-row chunk
  int scol = ((lane & 7) ^ (lane >> 3)) << 3;         // SWIZZLED source col (u16)

  f32x4 acc[FM][FN];
#pragma unroll
  for (int m = 0; m < FM; m++)
#pragma unroll
    for (int n = 0; n < FN; n++) acc[m][n] = (f32x4){0.f, 0.f, 0.f, 0.f};

  for (int k0 = 0; k0 < K; k0 += BK) {
    // ---- stage tile: linear LDS dest + swizzled global source (rule #21)
#pragma unroll
    for (int i = 0; i < ACH; i++) {
      int c = wid * ACH + i;
      int row = c * 8 + srow;
      int grow = bm0 + row;
      if (grow > M - 1) grow = M - 1;
      gload_lds16(A + (size_t)grow * K + k0 + scol, lA + c * 512);
    }
#pragma unroll
    for (int i = 0; i < BCH; i++) {
      int c = wid * BCH + i;
      int row = c * 8 + srow;
      gload_lds16(Bt + (size_t)(bn0 + row) * K + k0 + scol, lB + c * 512);
    }
    __syncthreads();  // drains vmcnt(0) -> LDS tile ready

    // ---- MFMA over BK (2 x k=32 steps), swizzled reads
    int swz = (lane & 7) << 4;
#pragma unroll
    for (int ks = 0; ks < 2; ks++) {
      int kb = ks * 64 + ((lane >> 4) << 4);  // linear byte offset in 128B row
      s16x8 af[FM], bf[FN];
#pragma unroll
      for (int m = 0; m < FM; m++) {
        int row = wm * WTM + m * 16 + (lane & 15);
        af[m] = *(const s16x8*)((const char*)lA + row * 128 + (kb ^ swz));
      }
#pragma unroll
      for (int n = 0; n < FN; n++) {
        int row = wn * WTN + n * 16 + (lane & 15);
        bf[n] = *(const s16x8*)((const char*)lB + row * 128 + (kb ^ swz));
      }
#pragma unroll
      for (int m = 0; m < FM; m++)
#pragma unroll
        for (int n = 0; n < FN; n++)
          acc[m][n] = __builtin_amdgcn_mfma_f32_16x16x32_bf16(af[m], bf[n], acc[m][n], 0, 0, 0);
    }
    __syncthreads();  // LDS consumed; safe to restage
  }

  // ---- epilogue: bias/relu, optional fused hs/hd dots, LDS-staged C store
  u16* lC = smem;  // BM*BN u16 <= (BM+BN)*BK for our configs
  int r0 = (lane >> 4) * 4;
  int head = hs ? (bn0 / Cc) : 0;
  int part = hs ? ((bn0 % Cc) / WTN + wn) : 0;   // wave-unique column slice
  float asv[FN], adv[FN];
  float sa[FM][4], da[FM][4];
  if (hs) {
#pragma unroll
    for (int n = 0; n < FN; n++) {
      int colC = (bn0 % Cc) + wn * WTN + n * 16 + (lane & 15);
      asv[n] = ldf(asrc, (size_t)head * Cc + colC, isbf);
      adv[n] = ldf(adst, (size_t)head * Cc + colC, isbf);
    }
#pragma unroll
    for (int m = 0; m < FM; m++)
#pragma unroll
      for (int rr = 0; rr < 4; rr++) { sa[m][rr] = 0.f; da[m][rr] = 0.f; }
  }
#pragma unroll
  for (int m = 0; m < FM; m++)
#pragma unroll
    for (int n = 0; n < FN; n++)
#pragma unroll
      for (int rr = 0; rr < 4; rr++) {
        int row = wm * WTM + m * 16 + r0 + rr;
        int col = wn * WTN + n * 16 + (lane & 15);
        float v = acc[m][n][rr];
        if (bias) v += ldf(bias, bn0 + col, isbf);
        if (do_relu) v = fmaxf(v, 0.f);
        if (hs) { sa[m][rr] += v * asv[n]; da[m][rr] += v * adv[n]; }
        lC[row * BN + col] = f2b(v);
      }
  if (hs) {
#pragma unroll
    for (int m = 0; m < FM; m++) {
#pragma unroll
      for (int mask = 1; mask < 16; mask <<= 1)
#pragma unroll
        for (int rr = 0; rr < 4; rr++) {
          sa[m][rr] += __shfl_xor(sa[m][rr], mask);
          da[m][rr] += __shfl_xor(da[m][rr], mask);
        }
      if ((lane & 15) == 0) {
#pragma unroll
        for (int rr = 0; rr < 4; rr++) {
          int grow = bm0 + wm * WTM + m * 16 + r0 + rr;
          if (grow < M) {
            hs[((size_t)grow * H + head) * 4 + part] = sa[m][rr];
            hd[((size_t)grow * H + head) * 4 + part] = da[m][rr];
          }
        }
      }
    }
  }
  __syncthreads();
  constexpr int CHUNKS = BM * BN / 2048;  // 16B chunks per thread
  constexpr int CPR = BN / 8;             // chunks per C row
#pragma unroll
  for (int j = 0; j < CHUNKS; j++) {
    int idx = j * 256 + tid;
    int row = idx / CPR, colb = (idx % CPR) * 16;
    int grow = bm0 + row;
    if (grow < M) {
      int4 v = *(const int4*)((const char*)lC + idx * 16);
      *(int4*)((char*)C + ((size_t)grow * N + bn0) * 2 + colb) = v;
    }
  }
}

// ---------------------------------------------------------------- edge softmax
// hs/hd hold 4 wave-partials per (node,head): one float4 load, sum components.
__global__ void softmax_kernel(const int* __restrict__ csr_src, const int* __restrict__ offs,
                               const float* __restrict__ hs, const float* __restrict__ hd,
                               float* __restrict__ alpha, int H, int n) {
  int idx = blockIdx.x * blockDim.x + threadIdx.x;
  if (idx >= n * H) return;
  int i = idx / H, hh = idx % H;
  const float4* hs4 = (const float4*)hs;
  float4 hdp = ((const float4*)hd)[idx];
  float hdv = (hdp.x + hdp.y) + (hdp.z + hdp.w);
  int p0 = offs[i], p1 = offs[i + 1];
  float m = -1e30f;
  for (int p = p0; p < p1; ++p) {
    float4 hp = hs4[(size_t)csr_src[p] * H + hh];
    float e = (hp.x + hp.y) + (hp.z + hp.w) + hdv;
    e = e > 0.f ? e : 0.2f * e;
    alpha[(size_t)p * H + hh] = e;
    m = fmaxf(m, e);
  }
  float den = 0.f;
  for (int p = p0; p < p1; ++p) {
    float pe = __expf(alpha[(size_t)p * H + hh] - m);
    alpha[(size_t)p * H + hh] = pe;
    den += pe;
  }
  float inv = 1.f / (den + 1e-16f);
  for (int p = p0; p < p1; ++p) alpha[(size_t)p * H + hh] *= inv;
}

// ---------------------------------------------------------------- aggregation
template <int HC, int VPT, int TPB>
__global__ __launch_bounds__(TPB) void aggregate_kernel(
    const u16* __restrict__ h, const float* __restrict__ alpha,
    const int* __restrict__ csr_src, const int* __restrict__ offs,
    const void* __restrict__ bias, u16* __restrict__ outb, void* __restrict__ outv,
    int H, int C, int do_elu, const int* __restrict__ FLAG) {
  int isbf = *FLAG;
  int i = blockIdx.x;
  int t = threadIdx.x;
  int c0 = t * VPT;
  int head = c0 / C;
  float acc[VPT];
#pragma unroll
  for (int j = 0; j < VPT; j++) acc[j] = 0.f;
  int p0 = offs[i], p1 = offs[i + 1];
  int p = p0;
  for (; p + 2 <= p1; p += 2) {  // unroll x2: two row reads in flight
    int s0 = csr_src[p], s1 = csr_src[p + 1];
    float a0 = alpha[(size_t)p * H + head];
    float a1 = alpha[(size_t)(p + 1) * H + head];
    const u16* h0 = h + (size_t)s0 * HC + c0;
    const u16* h1 = h + (size_t)s1 * HC + c0;
    if constexpr (VPT == 8) {
      u16x8 v0 = *(const u16x8*)h0, v1 = *(const u16x8*)h1;
#pragma unroll
      for (int j = 0; j < 8; j++) acc[j] += a0 * b2f(v0[j]) + a1 * b2f(v1[j]);
    } else if constexpr (VPT == 4) {
      u16x4 v0 = *(const u16x4*)h0, v1 = *(const u16x4*)h1;
#pragma unroll
      for (int j = 0; j < 4; j++) acc[j] += a0 * b2f(v0[j]) + a1 * b2f(v1[j]);
    } else {
      acc[0] += a0 * b2f(h0[0]) + a1 * b2f(h1[0]);
    }
  }
  if (p < p1) {
    int s0 = csr_src[p];
    float a0 = alpha[(size_t)p * H + head];
    const u16* h0 = h + (size_t)s0 * HC + c0;
    if constexpr (VPT == 8) {
      u16x8 v0 = *(const u16x8*)h0;
#pragma unroll
      for (int j = 0; j < 8; j++) acc[j] += a0 * b2f(v0[j]);
    } else if constexpr (VPT == 4) {
      u16x4 v0 = *(const u16x4*)h0;
#pragma unroll
      for (int j = 0; j < 4; j++) acc[j] += a0 * b2f(v0[j]);
    } else {
      acc[0] += a0 * b2f(h0[0]);
    }
  }
  float r[VPT];
#pragma unroll
  for (int j = 0; j < VPT; j++) {
    r[j] = acc[j] + ldf(bias, c0 + j, isbf);
    if (do_elu) r[j] = r[j] > 0.f ? r[j] : expm1f(r[j]);
  }
  if (outb) {
    if constexpr (VPT == 8) {
      u16x8 o;
#pragma unroll
      for (int j = 0; j < 8; j++) o[j] = f2b(r[j]);
      *(u16x8*)(outb + (size_t)i * HC + c0) = o;
    } else if constexpr (VPT == 4) {
      u16x4 o;
#pragma unroll
      for (int j = 0; j < 4; j++) o[j] = f2b(r[j]);
      *(u16x4*)(outb + (size_t)i * HC + c0) = o;
    } else {
      outb[(size_t)i * HC + c0] = f2b(r[0]);
    }
  }
  if (outv) {
#pragma unroll
    for (int j = 0; j < VPT; j++)
      stf(outv, (size_t)10000 + (size_t)i * HC + c0 + j, isbf, r[j]);
  }
}

// ---------------------------------------------------------------- final dot (h2[128] . r3w + r3b)
__global__ __launch_bounds__(256) void dot128_kernel(const u16* __restrict__ h2,
                                                     const void* __restrict__ r3w,
                                                     const void* __restrict__ r3b,
                                                     void* __restrict__ scores,
                                                     const int* __restrict__ FLAG) {
  int isbf = *FLAG;
  int wid = threadIdx.x >> 6, lane = threadIdx.x & 63;
  int i = blockIdx.x * 4 + wid;
  if (i >= NN) return;
  const u16* hp = h2 + (size_t)i * 128;
  float v = b2f(hp[lane]) * ldf(r3w, lane, isbf) +
            b2f(hp[lane + 64]) * ldf(r3w, lane + 64, isbf);
  for (int o = 32; o; o >>= 1) v += __shfl_down(v, o);
  if (lane == 0) stf(scores, i, isbf, v + ldf(r3b, 0, isbf));
}

// ---------------------------------------------------------------- launch
extern "C" void kernel_launch(void* const* d_in, const int* in_sizes, int n_in,
                              void* d_out, int out_size, void* d_ws, size_t ws_size,
                              hipStream_t stream) {
  const void* x   = d_in[0];
  const int* ei   = (const int*)d_in[1];
  const void* W1  = d_in[2];
  const void* as1 = d_in[3];
  const void* ad1 = d_in[4];
  const void* b1  = d_in[5];
  const void* W2  = d_in[6];
  const void* as2 = d_in[7];
  const void* ad2 = d_in[8];
  const void* b2  = d_in[9];
  const void* W3  = d_in[10];
  const void* as3 = d_in[11];
  const void* ad3 = d_in[12];
  const void* b3  = d_in[13];
  const void* r1w = d_in[14];
  const void* r1b = d_in[15];
  const void* r2w = d_in[16];
  const void* r2b = d_in[17];
  const void* r3w = d_in[18];
  const void* r3b = d_in[19];

  char* ws = (char*)d_ws;
  size_t o = 0;
  auto alloc = [&](size_t bytes) { void* p = ws + o; o += (bytes + 255) & ~(size_t)255; return p; };
  u16* XC     = (u16*)alloc((size_t)NN * 768 * 2);
  u16* W1T    = (u16*)alloc((size_t)2048 * 768 * 2);
  u16* W2T    = (u16*)alloc((size_t)1024 * 2048 * 2);
  u16* W3T    = (u16*)alloc((size_t)64 * 1024 * 2);
  u16* R1T    = (u16*)alloc((size_t)256 * 64 * 2);
  u16* R2T    = (u16*)alloc((size_t)128 * 256 * 2);
  u16* Hbuf   = (u16*)alloc((size_t)NN * 2048 * 2);
  u16* Xbuf   = (u16*)alloc((size_t)NN * 2048 * 2);
  u16* X3B    = (u16*)alloc((size_t)NN * 64 * 2);
  u16* H1B    = (u16*)alloc((size_t)NN * 256 * 2);
  u16* H2B    = (u16*)alloc((size_t)NN * 128 * 2);
  // partial-sum layout: [node][head][4] floats per array
  float* HZ   = (float*)alloc((size_t)NN * 104 * 4);
  float* HS1  = HZ;                        // NN*8*4
  float* HD1  = HZ + (size_t)NN * 32;      // NN*8*4
  float* HS2  = HZ + (size_t)NN * 64;      // NN*4*4
  float* HD2  = HZ + (size_t)NN * 80;      // NN*4*4
  float* HS3  = HZ + (size_t)NN * 96;      // NN*1*4
  float* HD3  = HZ + (size_t)NN * 100;     // NN*1*4
  int* DEG    = (int*)alloc((size_t)NN * 4);
  int* OFFS   = (int*)alloc((size_t)(NN + 1) * 4);
  int* CURSOR = (int*)alloc((size_t)NN * 4);
  int* CSR    = (int*)alloc((size_t)NTOT * 4);
  float* ALPHA = (float*)alloc((size_t)NTOT * 8 * 4);
  int* FLAG   = (int*)alloc(256);

  detect_kernel<<<1, 64, 0, stream>>>(x, FLAG);
  cvt_kernel<<<(NN * 768 + 255) / 256, 256, 0, stream>>>(x, XC, NN * 768, FLAG);

  // batched weight transposes
  TD5 td;
  td.d[0] = {W1,  W1T, 768, 2048, 0};
  td.d[1] = {W2,  W2T, 2048, 1024, 0};
  td.d[2] = {W3,  W3T, 1024, 64, 0};
  td.d[3] = {r1w, R1T, 64, 256, 0};
  td.d[4] = {r2w, R2T, 256, 128, 0};
  int cum = 0;
  for (int k = 0; k < 5; k++) {
    td.d[k].t0 = cum;
    cum += (td.d[k].R / 32) * (td.d[k].C / 32);
  }
  transpose_all<<<cum, dim3(32, 8), 0, stream>>>(td, FLAG);

  init_kernel<<<(NN * 104 + 255) / 256, 256, 0, stream>>>(DEG, HZ, NN * 104);
  count_deg_kernel<<<(NE + 255) / 256, 256, 0, stream>>>(ei, DEG);
  scan_kernel<<<1, 1024, 0, stream>>>(DEG, OFFS, CURSOR, NN);
  scatter_kernel<<<(NTOT + 255) / 256, 256, 0, stream>>>(ei, CURSOR, CSR);

  const int MT = (NN + 127) / 128;   // 79
  const int MT64 = (NN + 63) / 64;   // 157

  // ---- layer 1: 768 -> 8 x 256 (fused hs/hd wave-partial dots; 64x128 tile)
  gemm_kernel<64, 128, 2, 2><<<MT64 * 16, 256, 0, stream>>>(
      XC, W1T, Hbuf, NN, 768, 2048, 16, nullptr, 0, as1, ad1, HS1, HD1, 8, 256, FLAG);
  softmax_kernel<<<(NN * 8 + 255) / 256, 256, 0, stream>>>(CSR, OFFS, HS1, HD1, ALPHA, 8, NN);
  aggregate_kernel<2048, 8, 256><<<NN, 256, 0, stream>>>(Hbuf, ALPHA, CSR, OFFS, b1, Xbuf, nullptr, 8, 256, 1, FLAG);

  // ---- layer 2: 2048 -> 4 x 256
  gemm_kernel<64, 128, 2, 2><<<MT64 * 8, 256, 0, stream>>>(
      Xbuf, W2T, Hbuf, NN, 2048, 1024, 8, nullptr, 0, as2, ad2, HS2, HD2, 4, 256, FLAG);
  softmax_kernel<<<(NN * 4 + 255) / 256, 256, 0, stream>>>(CSR, OFFS, HS2, HD2, ALPHA, 4, NN);
  aggregate_kernel<1024, 4, 256><<<NN, 256, 0, stream>>>(Hbuf, ALPHA, CSR, OFFS, b2, Xbuf, nullptr, 4, 256, 1, FLAG);

  // ---- layer 3: 1024 -> 1 x 64 (WTN=64=Cc -> single partial slot 0)
  gemm_kernel<128, 64, 4, 1><<<MT, 256, 0, stream>>>(
      Xbuf, W3T, Hbuf, NN, 1024, 64, 1, nullptr, 0, as3, ad3, HS3, HD3, 1, 64, FLAG);
  softmax_kernel<<<(NN + 255) / 256, 256, 0, stream>>>(CSR, OFFS, HS3, HD3, ALPHA, 1, NN);
  aggregate_kernel<64, 1, 64><<<NN, 64, 0, stream>>>(Hbuf, ALPHA, CSR, OFFS, b3, X3B, d_out, 1, 64, 0, FLAG);

  // ---- reasoning MLP as MFMA GEMMs + final dot
  gemm_kernel<64, 64, 2, 2><<<MT64 * 4, 256, 0, stream>>>(
      X3B, R1T, H1B, NN, 64, 256, 4, r1b, 1, nullptr, nullptr, nullptr, nullptr, 0, 0, FLAG);
  gemm_kernel<64, 64, 2, 2><<<MT64 * 2, 256, 0, stream>>>(
      H1B, R2T, H2B, NN, 256, 128, 2, r2b, 1, nullptr, nullptr, nullptr, nullptr, 0, 0, FLAG);
  dot128_kernel<<<(NN + 3) / 4, 256, 0, stream>>>(H2B, r3w, r3b, d_out, FLAG);
}

// Round 10
// 344.301 us; speedup vs baseline: 2.3411x; 1.0926x over previous
//
#include <hip/hip_runtime.h>
#include <stdint.h>

typedef unsigned short u16;
using s16x8 = __attribute__((ext_vector_type(8))) short;
using f32x4 = __attribute__((ext_vector_type(4))) float;
using u16x8 = __attribute__((ext_vector_type(8))) unsigned short;
using u16x4 = __attribute__((ext_vector_type(4))) unsigned short;

#define DEVINL __device__ __forceinline__

DEVINL float b2f(u16 u) { return __uint_as_float(((uint32_t)u) << 16); }
DEVINL u16 f2b(float f) {
  uint32_t x = __float_as_uint(f);
  return (u16)((x + 0x7fffu + ((x >> 16) & 1u)) >> 16);
}
// dtype-agnostic load/store: isbf=1 -> bf16 (u16), else fp32
DEVINL float ldf(const void* p, size_t i, int isbf) {
  return isbf ? b2f(((const u16*)p)[i]) : ((const float*)p)[i];
}
DEVINL void stf(void* p, size_t i, int isbf, float v) {
  if (isbf) ((u16*)p)[i] = f2b(v);
  else      ((float*)p)[i] = v;
}

typedef __attribute__((address_space(1))) const void gvoid;
typedef __attribute__((address_space(3))) void lvoid;
DEVINL void gload_lds16(const u16* g, u16* l) {
  __builtin_amdgcn_global_load_lds((gvoid*)g, (lvoid*)l, 16, 0, 0);
}

constexpr int NN = 10000;     // nodes
constexpr int NE = 80000;     // edges (no self loops)
constexpr int NTOT = 90000;   // edges + self loops

// ---------------------------------------------------------------- dtype detect
__global__ void detect_kernel(const void* __restrict__ x, int* __restrict__ flag) {
  int lane = threadIdx.x;  // 64
  u16 w = ((const u16*)x)[lane * 97 + 13];
  int e = (w >> 7) & 0xFF;
  int sane = (e >= 0x50 && e <= 0x8A) ? 1 : 0;
  unsigned long long b = __ballot(sane);
  if (lane == 0) flag[0] = (__popcll(b) >= 56) ? 1 : 0;
}

// canonicalize x -> bf16
__global__ void cvt_kernel(const void* __restrict__ in, u16* __restrict__ out,
                           int n, const int* __restrict__ FLAG) {
  int isbf = *FLAG;
  int i = blockIdx.x * 256 + threadIdx.x;
  if (i >= n) return;
  out[i] = isbf ? ((const u16*)in)[i] : f2b(((const float*)in)[i]);
}

// ---------------------------------------------------------------- batched transpose
struct TD { const void* in; u16* out; int R, C, t0; };
struct TD5 { TD d[5]; };
__global__ void transpose_all(TD5 td, const int* __restrict__ FLAG) {
  int isbf = *FLAG;
  __shared__ float tile[32][33];
  int t = blockIdx.x;
  int k = 0;
#pragma unroll
  for (int j = 1; j < 5; j++) if (t >= td.d[j].t0) k = j;
  const void* in = td.d[k].in;
  u16* out = td.d[k].out;
  int R = td.d[k].R, C = td.d[k].C;
  int tl = t - td.d[k].t0;
  int tcols = C / 32;
  int bx = (tl % tcols) * 32, by = (tl / tcols) * 32;
  int tx = threadIdx.x, ty = threadIdx.y;  // (32,8)
  for (int j = 0; j < 32; j += 8) {
    int r = by + ty + j, c = bx + tx;
    tile[ty + j][tx] = ldf(in, (size_t)r * C + c, isbf);
  }
  __syncthreads();
  for (int j = 0; j < 32; j += 8) {
    int r = bx + ty + j, c = by + tx;
    out[(size_t)r * R + c] = f2b(tile[tx][ty + j]);
  }
}

// ---------------------------------------------------------------- CSR build + zero HS/HD
__global__ void init_kernel(int* __restrict__ deg, float* __restrict__ hz, int nz) {
  int i = blockIdx.x * blockDim.x + threadIdx.x;
  if (i < NN) deg[i] = 1;  // self loop
  if (i < nz) hz[i] = 0.f;
}

__global__ void count_deg_kernel(const int* __restrict__ ei, int* __restrict__ deg) {
  int e = blockIdx.x * blockDim.x + threadIdx.x;
  if (e < NE) atomicAdd(&deg[ei[NE + e]], 1);
}

__global__ __launch_bounds__(1024) void scan_kernel(const int* __restrict__ deg,
                                                    int* __restrict__ offs,
                                                    int* __restrict__ cursor, int n) {
  __shared__ int wsum[16];
  __shared__ int carry_s;
  int tid = threadIdx.x, lane = tid & 63, wid = tid >> 6;
  if (tid == 0) carry_s = 0;
  __syncthreads();
  for (int base = 0; base < n; base += 1024) {
    int idx = base + tid;
    int v = (idx < n) ? deg[idx] : 0;
    int s = v;
#pragma unroll
    for (int o = 1; o < 64; o <<= 1) { int t = __shfl_up(s, o); if (lane >= o) s += t; }
    if (lane == 63) wsum[wid] = s;
    __syncthreads();
    if (wid == 0) {
      int w = (lane < 16) ? wsum[lane] : 0;
#pragma unroll
      for (int o = 1; o < 16; o <<= 1) { int t = __shfl_up(w, o); if (lane >= o) w += t; }
      if (lane < 16) wsum[lane] = w;
    }
    __syncthreads();
    int inc = s + (wid > 0 ? wsum[wid - 1] : 0) + carry_s;
    if (idx < n) { offs[idx + 1] = inc; cursor[idx] = inc - v; }
    __syncthreads();
    if (tid == 0) carry_s += wsum[15];
    __syncthreads();
  }
  if (tid == 0) offs[0] = 0;
}

__global__ void scatter_kernel(const int* __restrict__ ei, int* __restrict__ cursor,
                               int* __restrict__ csr_src) {
  int e = blockIdx.x * blockDim.x + threadIdx.x;
  if (e >= NTOT) return;
  int s, d;
  if (e < NE) { s = ei[e]; d = ei[NE + e]; }
  else        { s = e - NE; d = s; }
  int pos = atomicAdd(&cursor[d], 1);
  csr_src[pos] = s;
}

// ---------------------------------------------------------------- GEMM (bf16 MFMA)
// C[M,N] = A[M,K] * Bt[N,K]^T. m97 structure + both-sides swizzle + XCD remap
// + LDS-staged coalesced C store (skipped when C==null) + optional fused
// {bias,relu} and fused dots. hs/hd partials are WAVE-UNIQUE:
// part = (bn0 % Cc)/WTN + wn; stored at hs[(row*H+head)*4 + part].
template <int BM, int BN, int WM, int WN>
__global__ __launch_bounds__(256) void gemm_kernel(const u16* __restrict__ A,
                                                   const u16* __restrict__ Bt,
                                                   u16* __restrict__ C,
                                                   int M, int K, int N, int nN,
                                                   const void* __restrict__ bias,
                                                   int do_relu,
                                                   const void* __restrict__ asrc,
                                                   const void* __restrict__ adst,
                                                   float* __restrict__ hs,
                                                   float* __restrict__ hd,
                                                   int H, int Cc,
                                                   const int* __restrict__ FLAG) {
  constexpr int BK = 64;             // 128 B per LDS row
  constexpr int WTM = BM / WM, WTN = BN / WN;
  constexpr int FM = WTM / 16, FN = WTN / 16;
  constexpr int ACH = BM / 32;       // 1KB staging chunks per wave (A)
  constexpr int BCH = BN / 32;

  __shared__ u16 smem[(BM + BN) * BK];
  u16* lA = smem;
  u16* lB = smem + BM * BK;

  int tid = threadIdx.x;
  int lane = tid & 63, wid = tid >> 6;
  int wm = wid / WN, wn = wid % WN;
  int isbf = (bias || asrc) ? *FLAG : 0;

  // bijective XCD remap (m204)
  int nwg = gridDim.x;
  int q = nwg >> 3, r = nwg & 7;
  int xcd = blockIdx.x & 7, pos = blockIdx.x >> 3;
  int wgid = (xcd < r ? xcd * (q + 1) : r * (q + 1) + (xcd - r) * q) + pos;
  int bm0 = (wgid / nN) * BM, bn0 = (wgid % nN) * BN;

  int srow = lane >> 3;                               // row within 8-row chunk
  int scol = ((lane & 7) ^ (lane >> 3)) << 3;         // SWIZZLED source col (u16)

  f32x4 acc[FM][FN];
#pragma unroll
  for (int m = 0; m < FM; m++)
#pragma unroll
    for (int n = 0; n < FN; n++) acc[m][n] = (f32x4){0.f, 0.f, 0.f, 0.f};

  for (int k0 = 0; k0 < K; k0 += BK) {
    // ---- stage tile: linear LDS dest + swizzled global source (rule #21)
#pragma unroll
    for (int i = 0; i < ACH; i++) {
      int c = wid * ACH + i;
      int row = c * 8 + srow;
      int grow = bm0 + row;
      if (grow > M - 1) grow = M - 1;
      gload_lds16(A + (size_t)grow * K + k0 + scol, lA + c * 512);
    }
#pragma unroll
    for (int i = 0; i < BCH; i++) {
      int c = wid * BCH + i;
      int row = c * 8 + srow;
      gload_lds16(Bt + (size_t)(bn0 + row) * K + k0 + scol, lB + c * 512);
    }
    __syncthreads();  // drains vmcnt(0) -> LDS tile ready

    // ---- MFMA over BK (2 x k=32 steps), swizzled reads
    int swz = (lane & 7) << 4;
#pragma unroll
    for (int ks = 0; ks < 2; ks++) {
      int kb = ks * 64 + ((lane >> 4) << 4);  // linear byte offset in 128B row
      s16x8 af[FM], bf[FN];
#pragma unroll
      for (int m = 0; m < FM; m++) {
        int row = wm * WTM + m * 16 + (lane & 15);
        af[m] = *(const s16x8*)((const char*)lA + row * 128 + (kb ^ swz));
      }
#pragma unroll
      for (int n = 0; n < FN; n++) {
        int row = wn * WTN + n * 16 + (lane & 15);
        bf[n] = *(const s16x8*)((const char*)lB + row * 128 + (kb ^ swz));
      }
#pragma unroll
      for (int m = 0; m < FM; m++)
#pragma unroll
        for (int n = 0; n < FN; n++)
          acc[m][n] = __builtin_amdgcn_mfma_f32_16x16x32_bf16(af[m], bf[n], acc[m][n], 0, 0, 0);
    }
    __syncthreads();  // LDS consumed; safe to restage
  }

  // ---- epilogue: bias/relu, optional fused dots, LDS-staged C store
  u16* lC = smem;  // BM*BN u16 <= (BM+BN)*BK for our configs
  int r0 = (lane >> 4) * 4;
  int head = hs ? (bn0 / Cc) : 0;
  int part = hs ? ((bn0 % Cc) / WTN + wn) : 0;   // wave-unique column slice
  float asv[FN], adv[FN];
  float sa[FM][4], da[FM][4];
  if (hs) {
#pragma unroll
    for (int n = 0; n < FN; n++) {
      int colC = (bn0 % Cc) + wn * WTN + n * 16 + (lane & 15);
      asv[n] = ldf(asrc, (size_t)head * Cc + colC, isbf);
      adv[n] = ldf(adst, (size_t)head * Cc + colC, isbf);
    }
#pragma unroll
    for (int m = 0; m < FM; m++)
#pragma unroll
      for (int rr = 0; rr < 4; rr++) { sa[m][rr] = 0.f; da[m][rr] = 0.f; }
  }
#pragma unroll
  for (int m = 0; m < FM; m++)
#pragma unroll
    for (int n = 0; n < FN; n++)
#pragma unroll
      for (int rr = 0; rr < 4; rr++) {
        int row = wm * WTM + m * 16 + r0 + rr;
        int col = wn * WTN + n * 16 + (lane & 15);
        float v = acc[m][n][rr];
        if (bias) v += ldf(bias, bn0 + col, isbf);
        if (do_relu) v = fmaxf(v, 0.f);
        if (hs) { sa[m][rr] += v * asv[n]; da[m][rr] += v * adv[n]; }
        lC[row * BN + col] = f2b(v);
      }
  if (hs) {
#pragma unroll
    for (int m = 0; m < FM; m++) {
#pragma unroll
      for (int mask = 1; mask < 16; mask <<= 1)
#pragma unroll
        for (int rr = 0; rr < 4; rr++) {
          sa[m][rr] += __shfl_xor(sa[m][rr], mask);
          da[m][rr] += __shfl_xor(da[m][rr], mask);
        }
      if ((lane & 15) == 0) {
#pragma unroll
        for (int rr = 0; rr < 4; rr++) {
          int grow = bm0 + wm * WTM + m * 16 + r0 + rr;
          if (grow < M) {
            hs[((size_t)grow * H + head) * 4 + part] = sa[m][rr];
            hd[((size_t)grow * H + head) * 4 + part] = da[m][rr];
          }
        }
      }
    }
  }
  if (C) {
    __syncthreads();
    constexpr int CHUNKS = BM * BN / 2048;  // 16B chunks per thread
    constexpr int CPR = BN / 8;             // chunks per C row
#pragma unroll
    for (int j = 0; j < CHUNKS; j++) {
      int idx = j * 256 + tid;
      int row = idx / CPR, colb = (idx % CPR) * 16;
      int grow = bm0 + row;
      if (grow < M) {
        int4 v = *(const int4*)((const char*)lC + idx * 16);
        *(int4*)((char*)C + ((size_t)grow * N + bn0) * 2 + colb) = v;
      }
    }
  }
}

// ---------------------------------------------------------------- fused softmax + aggregation
// One block per dst node. Crew (H*32 threads) computes per-head max/denom via
// two passes over edges (shfl reductions in 32-lane groups), then fills LDS
// alpha per 64-edge chunk; all threads aggregate from LDS alpha.
template <int HC, int VPT, int TPB, int H>
__global__ __launch_bounds__(TPB) void agg_fused_kernel(
    const u16* __restrict__ h, const float* __restrict__ hs, const float* __restrict__ hd,
    const int* __restrict__ csr_src, const int* __restrict__ offs,
    const void* __restrict__ bias, u16* __restrict__ outb, void* __restrict__ outv,
    int do_elu, const int* __restrict__ FLAG) {
  constexpr int C = HC / H;
  constexpr int CH = 64;  // edge chunk
  int isbf = *FLAG;
  int i = blockIdx.x;
  int t = threadIdx.x;
  int p0 = offs[i], p1 = offs[i + 1];
  __shared__ float m_s[H], inv_s[H], hd_s[H];
  __shared__ float lalpha[CH * H];
  __shared__ int lsrc[CH];
  const float4* hs4 = (const float4*)hs;

  if (t < H) {
    float4 qd = ((const float4*)hd)[(size_t)i * H + t];
    hd_s[t] = (qd.x + qd.y) + (qd.z + qd.w);
  }
  __syncthreads();

  int hh = (t >> 5) % H, j = t & 31;
  bool crew = (t < H * 32);
  if (crew) {
    float hdv = hd_s[hh];
    float mm = -1e30f;
    for (int p = p0 + j; p < p1; p += 32) {
      float4 qv = hs4[(size_t)csr_src[p] * H + hh];
      float e = (qv.x + qv.y) + (qv.z + qv.w) + hdv;
      e = e > 0.f ? e : 0.2f * e;
      mm = fmaxf(mm, e);
    }
#pragma unroll
    for (int msk = 16; msk; msk >>= 1) mm = fmaxf(mm, __shfl_xor(mm, msk));
    float dd = 0.f;
    for (int p = p0 + j; p < p1; p += 32) {
      float4 qv = hs4[(size_t)csr_src[p] * H + hh];
      float e = (qv.x + qv.y) + (qv.z + qv.w) + hdv;
      e = e > 0.f ? e : 0.2f * e;
      dd += __expf(e - mm);
    }
#pragma unroll
    for (int msk = 16; msk; msk >>= 1) dd += __shfl_xor(dd, msk);
    if (j == 0) { m_s[hh] = mm; inv_s[hh] = 1.f / (dd + 1e-16f); }
  }

  int c0 = t * VPT;
  int head = c0 / C;
  float acc[VPT];
#pragma unroll
  for (int v = 0; v < VPT; v++) acc[v] = 0.f;

  for (int base = p0; base < p1; base += CH) {
    int cend = base + CH < p1 ? base + CH : p1;
    __syncthreads();  // m_s/inv_s ready (1st iter); lalpha consumers done (later)
    if (crew) {
      float hdv = hd_s[hh];
      float mmv = m_s[hh], inv = inv_s[hh];
      for (int p = base + j; p < cend; p += 32) {
        float4 qv = hs4[(size_t)csr_src[p] * H + hh];
        float e = (qv.x + qv.y) + (qv.z + qv.w) + hdv;
        e = e > 0.f ? e : 0.2f * e;
        lalpha[(p - base) * H + hh] = __expf(e - mmv) * inv;
      }
    }
    if (t < cend - base) lsrc[t] = csr_src[base + t];
    __syncthreads();

    int p = base;
    for (; p + 2 <= cend; p += 2) {  // unroll x2: two row reads in flight
      int s0 = lsrc[p - base], s1 = lsrc[p - base + 1];
      float a0 = lalpha[(p - base) * H + head];
      float a1 = lalpha[(p - base + 1) * H + head];
      const u16* h0 = h + (size_t)s0 * HC + c0;
      const u16* h1 = h + (size_t)s1 * HC + c0;
      if constexpr (VPT == 8) {
        u16x8 v0 = *(const u16x8*)h0, v1 = *(const u16x8*)h1;
#pragma unroll
        for (int v = 0; v < 8; v++) acc[v] += a0 * b2f(v0[v]) + a1 * b2f(v1[v]);
      } else if constexpr (VPT == 4) {
        u16x4 v0 = *(const u16x4*)h0, v1 = *(const u16x4*)h1;
#pragma unroll
        for (int v = 0; v < 4; v++) acc[v] += a0 * b2f(v0[v]) + a1 * b2f(v1[v]);
      } else {
        acc[0] += a0 * b2f(h0[0]) + a1 * b2f(h1[0]);
      }
    }
    if (p < cend) {
      int s0 = lsrc[p - base];
      float a0 = lalpha[(p - base) * H + head];
      const u16* h0 = h + (size_t)s0 * HC + c0;
      if constexpr (VPT == 8) {
        u16x8 v0 = *(const u16x8*)h0;
#pragma unroll
        for (int v = 0; v < 8; v++) acc[v] += a0 * b2f(v0[v]);
      } else if constexpr (VPT == 4) {
        u16x4 v0 = *(const u16x4*)h0;
#pragma unroll
        for (int v = 0; v < 4; v++) acc[v] += a0 * b2f(v0[v]);
      } else {
        acc[0] += a0 * b2f(h0[0]);
      }
    }
  }

  float r[VPT];
#pragma unroll
  for (int v = 0; v < VPT; v++) {
    r[v] = acc[v] + ldf(bias, c0 + v, isbf);
    if (do_elu) r[v] = r[v] > 0.f ? r[v] : expm1f(r[v]);
  }
  if (outb) {
    if constexpr (VPT == 8) {
      u16x8 o;
#pragma unroll
      for (int v = 0; v < 8; v++) o[v] = f2b(r[v]);
      *(u16x8*)(outb + (size_t)i * HC + c0) = o;
    } else if constexpr (VPT == 4) {
      u16x4 o;
#pragma unroll
      for (int v = 0; v < 4; v++) o[v] = f2b(r[v]);
      *(u16x4*)(outb + (size_t)i * HC + c0) = o;
    } else {
      outb[(size_t)i * HC + c0] = f2b(r[0]);
    }
  }
  if (outv) {
#pragma unroll
    for (int v = 0; v < VPT; v++)
      stf(outv, (size_t)10000 + (size_t)i * HC + c0 + v, isbf, r[v]);
  }
}

// ---------------------------------------------------------------- scores finish
__global__ void scores_kernel(const float* __restrict__ sc, const void* __restrict__ r3b,
                              void* __restrict__ scores, const int* __restrict__ FLAG) {
  int isbf = *FLAG;
  int i = blockIdx.x * 256 + threadIdx.x;
  if (i >= NN) return;
  float4 q = ((const float4*)sc)[i];
  stf(scores, i, isbf, (q.x + q.y) + (q.z + q.w) + ldf(r3b, 0, isbf));
}

// ---------------------------------------------------------------- launch
extern "C" void kernel_launch(void* const* d_in, const int* in_sizes, int n_in,
                              void* d_out, int out_size, void* d_ws, size_t ws_size,
                              hipStream_t stream) {
  const void* x   = d_in[0];
  const int* ei   = (const int*)d_in[1];
  const void* W1  = d_in[2];
  const void* as1 = d_in[3];
  const void* ad1 = d_in[4];
  const void* b1  = d_in[5];
  const void* W2  = d_in[6];
  const void* as2 = d_in[7];
  const void* ad2 = d_in[8];
  const void* b2  = d_in[9];
  const void* W3  = d_in[10];
  const void* as3 = d_in[11];
  const void* ad3 = d_in[12];
  const void* b3  = d_in[13];
  const void* r1w = d_in[14];
  const void* r1b = d_in[15];
  const void* r2w = d_in[16];
  const void* r2b = d_in[17];
  const void* r3w = d_in[18];
  const void* r3b = d_in[19];

  char* ws = (char*)d_ws;
  size_t o = 0;
  auto alloc = [&](size_t bytes) { void* p = ws + o; o += (bytes + 255) & ~(size_t)255; return p; };
  u16* XC     = (u16*)alloc((size_t)NN * 768 * 2);
  u16* W1T    = (u16*)alloc((size_t)2048 * 768 * 2);
  u16* W2T    = (u16*)alloc((size_t)1024 * 2048 * 2);
  u16* W3T    = (u16*)alloc((size_t)64 * 1024 * 2);
  u16* R1T    = (u16*)alloc((size_t)256 * 64 * 2);
  u16* R2T    = (u16*)alloc((size_t)128 * 256 * 2);
  u16* Hbuf   = (u16*)alloc((size_t)NN * 2048 * 2);
  u16* Xbuf   = (u16*)alloc((size_t)NN * 2048 * 2);
  u16* X3B    = (u16*)alloc((size_t)NN * 64 * 2);
  u16* H1B    = (u16*)alloc((size_t)NN * 256 * 2);
  // partial-sum layout: [node][head][4] floats per array
  float* HZ   = (float*)alloc((size_t)NN * 112 * 4);
  float* HS1  = HZ;                        // NN*8*4
  float* HD1  = HZ + (size_t)NN * 32;      // NN*8*4
  float* HS2  = HZ + (size_t)NN * 64;      // NN*4*4
  float* HD2  = HZ + (size_t)NN * 80;      // NN*4*4
  float* HS3  = HZ + (size_t)NN * 96;      // NN*1*4
  float* HD3  = HZ + (size_t)NN * 100;     // NN*1*4
  float* SC   = HZ + (size_t)NN * 104;     // NN*4 score partials
  float* SD   = HZ + (size_t)NN * 108;     // NN*4 dummy
  int* DEG    = (int*)alloc((size_t)NN * 4);
  int* OFFS   = (int*)alloc((size_t)(NN + 1) * 4);
  int* CURSOR = (int*)alloc((size_t)NN * 4);
  int* CSR    = (int*)alloc((size_t)NTOT * 4);
  int* FLAG   = (int*)alloc(256);

  detect_kernel<<<1, 64, 0, stream>>>(x, FLAG);
  cvt_kernel<<<(NN * 768 + 255) / 256, 256, 0, stream>>>(x, XC, NN * 768, FLAG);

  // batched weight transposes
  TD5 td;
  td.d[0] = {W1,  W1T, 768, 2048, 0};
  td.d[1] = {W2,  W2T, 2048, 1024, 0};
  td.d[2] = {W3,  W3T, 1024, 64, 0};
  td.d[3] = {r1w, R1T, 64, 256, 0};
  td.d[4] = {r2w, R2T, 256, 128, 0};
  int cum = 0;
  for (int k = 0; k < 5; k++) {
    td.d[k].t0 = cum;
    cum += (td.d[k].R / 32) * (td.d[k].C / 32);
  }
  transpose_all<<<cum, dim3(32, 8), 0, stream>>>(td, FLAG);

  init_kernel<<<(NN * 112 + 255) / 256, 256, 0, stream>>>(DEG, HZ, NN * 112);
  count_deg_kernel<<<(NE + 255) / 256, 256, 0, stream>>>(ei, DEG);
  scan_kernel<<<1, 1024, 0, stream>>>(DEG, OFFS, CURSOR, NN);
  scatter_kernel<<<(NTOT + 255) / 256, 256, 0, stream>>>(ei, CURSOR, CSR);

  const int MT = (NN + 127) / 128;   // 79
  const int MT64 = (NN + 63) / 64;   // 157

  // ---- layer 1: 768 -> 8 x 256 (fused hs/hd wave-partial dots; 64x128 tile)
  gemm_kernel<64, 128, 2, 2><<<MT64 * 16, 256, 0, stream>>>(
      XC, W1T, Hbuf, NN, 768, 2048, 16, nullptr, 0, as1, ad1, HS1, HD1, 8, 256, FLAG);
  agg_fused_kernel<2048, 8, 256, 8><<<NN, 256, 0, stream>>>(
      Hbuf, HS1, HD1, CSR, OFFS, b1, Xbuf, nullptr, 1, FLAG);

  // ---- layer 2: 2048 -> 4 x 256
  gemm_kernel<64, 128, 2, 2><<<MT64 * 8, 256, 0, stream>>>(
      Xbuf, W2T, Hbuf, NN, 2048, 1024, 8, nullptr, 0, as2, ad2, HS2, HD2, 4, 256, FLAG);
  agg_fused_kernel<1024, 4, 256, 4><<<NN, 256, 0, stream>>>(
      Hbuf, HS2, HD2, CSR, OFFS, b2, Xbuf, nullptr, 1, FLAG);

  // ---- layer 3: 1024 -> 1 x 64 (WTN=64=Cc -> single partial slot 0)
  gemm_kernel<128, 64, 4, 1><<<MT, 256, 0, stream>>>(
      Xbuf, W3T, Hbuf, NN, 1024, 64, 1, nullptr, 0, as3, ad3, HS3, HD3, 1, 64, FLAG);
  agg_fused_kernel<64, 1, 64, 1><<<NN, 64, 0, stream>>>(
      Hbuf, HS3, HD3, CSR, OFFS, b3, X3B, d_out, 0, FLAG);

  // ---- reasoning MLP as MFMA GEMMs; final dot fused into 2nd GEMM epilogue
  gemm_kernel<64, 64, 2, 2><<<MT64 * 4, 256, 0, stream>>>(
      X3B, R1T, H1B, NN, 64, 256, 4, r1b, 1, nullptr, nullptr, nullptr, nullptr, 0, 0, FLAG);
  gemm_kernel<64, 64, 2, 2><<<MT64 * 2, 256, 0, stream>>>(
      H1B, R2T, nullptr, NN, 256, 128, 2, r2b, 1, r3w, r3w, SC, SD, 1, 128, FLAG);
  scores_kernel<<<(NN + 255) / 256, 256, 0, stream>>>(SC, r3b, d_out, FLAG);
}

// Round 11
// 337.562 us; speedup vs baseline: 2.3879x; 1.0200x over previous
//
#include <hip/hip_runtime.h>
#include <stdint.h>

typedef unsigned short u16;
using s16x8 = __attribute__((ext_vector_type(8))) short;
using f32x4 = __attribute__((ext_vector_type(4))) float;
using u16x8 = __attribute__((ext_vector_type(8))) unsigned short;
using u16x4 = __attribute__((ext_vector_type(4))) unsigned short;

#define DEVINL __device__ __forceinline__

DEVINL float b2f(u16 u) { return __uint_as_float(((uint32_t)u) << 16); }
DEVINL u16 f2b(float f) {
  uint32_t x = __float_as_uint(f);
  return (u16)((x + 0x7fffu + ((x >> 16) & 1u)) >> 16);
}
// dtype-agnostic load/store: isbf=1 -> bf16 (u16), else fp32
DEVINL float ldf(const void* p, size_t i, int isbf) {
  return isbf ? b2f(((const u16*)p)[i]) : ((const float*)p)[i];
}
DEVINL void stf(void* p, size_t i, int isbf, float v) {
  if (isbf) ((u16*)p)[i] = f2b(v);
  else      ((float*)p)[i] = v;
}

typedef __attribute__((address_space(1))) const void gvoid;
typedef __attribute__((address_space(3))) void lvoid;
DEVINL void gload_lds16(const u16* g, u16* l) {
  __builtin_amdgcn_global_load_lds((gvoid*)g, (lvoid*)l, 16, 0, 0);
}

constexpr int NN = 10000;     // nodes
constexpr int NE = 80000;     // edges (no self loops)
constexpr int NTOT = 90000;   // edges + self loops

// ---------------------------------------------------------------- dtype detect
__global__ void detect_kernel(const void* __restrict__ x, int* __restrict__ flag) {
  int lane = threadIdx.x;  // 64
  u16 w = ((const u16*)x)[lane * 97 + 13];
  int e = (w >> 7) & 0xFF;
  int sane = (e >= 0x50 && e <= 0x8A) ? 1 : 0;
  unsigned long long b = __ballot(sane);
  if (lane == 0) flag[0] = (__popcll(b) >= 56) ? 1 : 0;
}

// canonicalize x -> bf16
__global__ void cvt_kernel(const void* __restrict__ in, u16* __restrict__ out,
                           int n, const int* __restrict__ FLAG) {
  int isbf = *FLAG;
  int i = blockIdx.x * 256 + threadIdx.x;
  if (i >= n) return;
  out[i] = isbf ? ((const u16*)in)[i] : f2b(((const float*)in)[i]);
}

// ---------------------------------------------------------------- batched transpose
struct TD { const void* in; u16* out; int R, C, t0; };
struct TD5 { TD d[5]; };
__global__ void transpose_all(TD5 td, const int* __restrict__ FLAG) {
  int isbf = *FLAG;
  __shared__ float tile[32][33];
  int t = blockIdx.x;
  int k = 0;
#pragma unroll
  for (int j = 1; j < 5; j++) if (t >= td.d[j].t0) k = j;
  const void* in = td.d[k].in;
  u16* out = td.d[k].out;
  int R = td.d[k].R, C = td.d[k].C;
  int tl = t - td.d[k].t0;
  int tcols = C / 32;
  int bx = (tl % tcols) * 32, by = (tl / tcols) * 32;
  int tx = threadIdx.x, ty = threadIdx.y;  // (32,8)
  for (int j = 0; j < 32; j += 8) {
    int r = by + ty + j, c = bx + tx;
    tile[ty + j][tx] = ldf(in, (size_t)r * C + c, isbf);
  }
  __syncthreads();
  for (int j = 0; j < 32; j += 8) {
    int r = bx + ty + j, c = by + tx;
    out[(size_t)r * R + c] = f2b(tile[tx][ty + j]);
  }
}

// ---------------------------------------------------------------- CSR build + zero HS/HD
__global__ void init_kernel(int* __restrict__ deg, float* __restrict__ hz, int nz) {
  int i = blockIdx.x * blockDim.x + threadIdx.x;
  if (i < NN) deg[i] = 1;  // self loop
  if (i < nz) hz[i] = 0.f;
}

__global__ void count_deg_kernel(const int* __restrict__ ei, int* __restrict__ deg) {
  int e = blockIdx.x * blockDim.x + threadIdx.x;
  if (e < NE) atomicAdd(&deg[ei[NE + e]], 1);
}

__global__ __launch_bounds__(1024) void scan_kernel(const int* __restrict__ deg,
                                                    int* __restrict__ offs,
                                                    int* __restrict__ cursor, int n) {
  __shared__ int wsum[16];
  __shared__ int carry_s;
  int tid = threadIdx.x, lane = tid & 63, wid = tid >> 6;
  if (tid == 0) carry_s = 0;
  __syncthreads();
  for (int base = 0; base < n; base += 1024) {
    int idx = base + tid;
    int v = (idx < n) ? deg[idx] : 0;
    int s = v;
#pragma unroll
    for (int o = 1; o < 64; o <<= 1) { int t = __shfl_up(s, o); if (lane >= o) s += t; }
    if (lane == 63) wsum[wid] = s;
    __syncthreads();
    if (wid == 0) {
      int w = (lane < 16) ? wsum[lane] : 0;
#pragma unroll
      for (int o = 1; o < 16; o <<= 1) { int t = __shfl_up(w, o); if (lane >= o) w += t; }
      if (lane < 16) wsum[lane] = w;
    }
    __syncthreads();
    int inc = s + (wid > 0 ? wsum[wid - 1] : 0) + carry_s;
    if (idx < n) { offs[idx + 1] = inc; cursor[idx] = inc - v; }
    __syncthreads();
    if (tid == 0) carry_s += wsum[15];
    __syncthreads();
  }
  if (tid == 0) offs[0] = 0;
}

__global__ void scatter_kernel(const int* __restrict__ ei, int* __restrict__ cursor,
                               int* __restrict__ csr_src) {
  int e = blockIdx.x * blockDim.x + threadIdx.x;
  if (e >= NTOT) return;
  int s, d;
  if (e < NE) { s = ei[e]; d = ei[NE + e]; }
  else        { s = e - NE; d = s; }
  int pos = atomicAdd(&cursor[d], 1);
  csr_src[pos] = s;
}

// ---------------------------------------------------------------- GEMM (bf16 MFMA)
// C[M,N] = A[M,K] * Bt[N,K]^T. m97 structure + both-sides swizzle + XCD remap
// + LDS-staged coalesced C store (skipped when C==null) + optional fused
// {bias,relu} and fused dots. hs/hd partials are WAVE-UNIQUE:
// part = (bn0 % Cc)/WTN + wn; stored at hs[(row*H+head)*4 + part].
template <int BM, int BN, int WM, int WN>
__global__ __launch_bounds__(256) void gemm_kernel(const u16* __restrict__ A,
                                                   const u16* __restrict__ Bt,
                                                   u16* __restrict__ C,
                                                   int M, int K, int N, int nN,
                                                   const void* __restrict__ bias,
                                                   int do_relu,
                                                   const void* __restrict__ asrc,
                                                   const void* __restrict__ adst,
                                                   float* __restrict__ hs,
                                                   float* __restrict__ hd,
                                                   int H, int Cc,
                                                   const int* __restrict__ FLAG) {
  constexpr int BK = 64;             // 128 B per LDS row
  constexpr int WTM = BM / WM, WTN = BN / WN;
  constexpr int FM = WTM / 16, FN = WTN / 16;
  constexpr int ACH = BM / 32;       // 1KB staging chunks per wave (A)
  constexpr int BCH = BN / 32;

  __shared__ u16 smem[(BM + BN) * BK];
  u16* lA = smem;
  u16* lB = smem + BM * BK;

  int tid = threadIdx.x;
  int lane = tid & 63, wid = tid >> 6;
  int wm = wid / WN, wn = wid % WN;
  int isbf = (bias || asrc) ? *FLAG : 0;

  // bijective XCD remap (m204)
  int nwg = gridDim.x;
  int q = nwg >> 3, r = nwg & 7;
  int xcd = blockIdx.x & 7, pos = blockIdx.x >> 3;
  int wgid = (xcd < r ? xcd * (q + 1) : r * (q + 1) + (xcd - r) * q) + pos;
  int bm0 = (wgid / nN) * BM, bn0 = (wgid % nN) * BN;

  int srow = lane >> 3;                               // row within 8-row chunk
  int scol = ((lane & 7) ^ (lane >> 3)) << 3;         // SWIZZLED source col (u16)

  f32x4 acc[FM][FN];
#pragma unroll
  for (int m = 0; m < FM; m++)
#pragma unroll
    for (int n = 0; n < FN; n++) acc[m][n] = (f32x4){0.f, 0.f, 0.f, 0.f};

  for (int k0 = 0; k0 < K; k0 += BK) {
    // ---- stage tile: linear LDS dest + swizzled global source (rule #21)
#pragma unroll
    for (int i = 0; i < ACH; i++) {
      int c = wid * ACH + i;
      int row = c * 8 + srow;
      int grow = bm0 + row;
      if (grow > M - 1) grow = M - 1;
      gload_lds16(A + (size_t)grow * K + k0 + scol, lA + c * 512);
    }
#pragma unroll
    for (int i = 0; i < BCH; i++) {
      int c = wid * BCH + i;
      int row = c * 8 + srow;
      gload_lds16(Bt + (size_t)(bn0 + row) * K + k0 + scol, lB + c * 512);
    }
    __syncthreads();  // drains vmcnt(0) -> LDS tile ready

    // ---- MFMA over BK (2 x k=32 steps), swizzled reads
    int swz = (lane & 7) << 4;
#pragma unroll
    for (int ks = 0; ks < 2; ks++) {
      int kb = ks * 64 + ((lane >> 4) << 4);  // linear byte offset in 128B row
      s16x8 af[FM], bf[FN];
#pragma unroll
      for (int m = 0; m < FM; m++) {
        int row = wm * WTM + m * 16 + (lane & 15);
        af[m] = *(const s16x8*)((const char*)lA + row * 128 + (kb ^ swz));
      }
#pragma unroll
      for (int n = 0; n < FN; n++) {
        int row = wn * WTN + n * 16 + (lane & 15);
        bf[n] = *(const s16x8*)((const char*)lB + row * 128 + (kb ^ swz));
      }
#pragma unroll
      for (int m = 0; m < FM; m++)
#pragma unroll
        for (int n = 0; n < FN; n++)
          acc[m][n] = __builtin_amdgcn_mfma_f32_16x16x32_bf16(af[m], bf[n], acc[m][n], 0, 0, 0);
    }
    __syncthreads();  // LDS consumed; safe to restage
  }

  // ---- epilogue: bias/relu, optional fused dots, LDS-staged C store
  u16* lC = smem;  // BM*BN u16 <= (BM+BN)*BK for our configs
  int r0 = (lane >> 4) * 4;
  int head = hs ? (bn0 / Cc) : 0;
  int part = hs ? ((bn0 % Cc) / WTN + wn) : 0;   // wave-unique column slice
  float asv[FN], adv[FN];
  float sa[FM][4], da[FM][4];
  if (hs) {
#pragma unroll
    for (int n = 0; n < FN; n++) {
      int colC = (bn0 % Cc) + wn * WTN + n * 16 + (lane & 15);
      asv[n] = ldf(asrc, (size_t)head * Cc + colC, isbf);
      adv[n] = ldf(adst, (size_t)head * Cc + colC, isbf);
    }
#pragma unroll
    for (int m = 0; m < FM; m++)
#pragma unroll
      for (int rr = 0; rr < 4; rr++) { sa[m][rr] = 0.f; da[m][rr] = 0.f; }
  }
#pragma unroll
  for (int m = 0; m < FM; m++)
#pragma unroll
    for (int n = 0; n < FN; n++)
#pragma unroll
      for (int rr = 0; rr < 4; rr++) {
        int row = wm * WTM + m * 16 + r0 + rr;
        int col = wn * WTN + n * 16 + (lane & 15);
        float v = acc[m][n][rr];
        if (bias) v += ldf(bias, bn0 + col, isbf);
        if (do_relu) v = fmaxf(v, 0.f);
        if (hs) { sa[m][rr] += v * asv[n]; da[m][rr] += v * adv[n]; }
        lC[row * BN + col] = f2b(v);
      }
  if (hs) {
#pragma unroll
    for (int m = 0; m < FM; m++) {
#pragma unroll
      for (int mask = 1; mask < 16; mask <<= 1)
#pragma unroll
        for (int rr = 0; rr < 4; rr++) {
          sa[m][rr] += __shfl_xor(sa[m][rr], mask);
          da[m][rr] += __shfl_xor(da[m][rr], mask);
        }
      if ((lane & 15) == 0) {
#pragma unroll
        for (int rr = 0; rr < 4; rr++) {
          int grow = bm0 + wm * WTM + m * 16 + r0 + rr;
          if (grow < M) {
            hs[((size_t)grow * H + head) * 4 + part] = sa[m][rr];
            hd[((size_t)grow * H + head) * 4 + part] = da[m][rr];
          }
        }
      }
    }
  }
  if (C) {
    __syncthreads();
    constexpr int CHUNKS = BM * BN / 2048;  // 16B chunks per thread
    constexpr int CPR = BN / 8;             // chunks per C row
#pragma unroll
    for (int j = 0; j < CHUNKS; j++) {
      int idx = j * 256 + tid;
      int row = idx / CPR, colb = (idx % CPR) * 16;
      int grow = bm0 + row;
      if (grow < M) {
        int4 v = *(const int4*)((const char*)lC + idx * 16);
        *(int4*)((char*)C + ((size_t)grow * N + bn0) * 2 + colb) = v;
      }
    }
  }
}

// ---------------------------------------------------------------- fused softmax + aggregation
// One block per dst node. Fast path (deg <= ECAP): crew gathers hs4 ONCE,
// caching e in LDS; max/denom/normalize passes are LDS-only and sync-free
// (lane-private stride). Aggregation reads alpha/src from LDS, unroll x4.
// Fallback (deg > ECAP): 3-global-pass chunked path.
template <int HC, int VPT, int TPB, int H, int ECAP>
__global__ __launch_bounds__(TPB) void agg_fused_kernel(
    const u16* __restrict__ h, const float* __restrict__ hs, const float* __restrict__ hd,
    const int* __restrict__ csr_src, const int* __restrict__ offs,
    const void* __restrict__ bias, u16* __restrict__ outb, void* __restrict__ outv,
    int do_elu, const int* __restrict__ FLAG) {
  constexpr int C = HC / H;
  constexpr int CH = 64;  // fallback edge chunk
  int isbf = *FLAG;
  int i = blockIdx.x;
  int t = threadIdx.x;
  int p0 = offs[i], p1 = offs[i + 1];
  int deg = p1 - p0;
  __shared__ float m_s[H], inv_s[H], hd_s[H];
  __shared__ float lalpha[ECAP * H];
  __shared__ int lsrc[ECAP];
  const float4* hs4 = (const float4*)hs;

  if (t < H) {
    float4 qd = ((const float4*)hd)[(size_t)i * H + t];
    hd_s[t] = (qd.x + qd.y) + (qd.z + qd.w);
  }
  __syncthreads();

  int hh = (t >> 5) % H, j = t & 31;
  bool crew = (t < H * 32);
  int c0 = t * VPT;
  int head = c0 / C;
  float acc[VPT];
#pragma unroll
  for (int v = 0; v < VPT; v++) acc[v] = 0.f;

  if (deg <= ECAP) {
    // ---------------- fast path: single global gather
    for (int idx = t; idx < deg; idx += TPB) lsrc[idx] = csr_src[p0 + idx];
    if (crew) {
      float hdv = hd_s[hh];
      float mm = -1e30f;
      for (int idx = j; idx < deg; idx += 32) {
        float4 qv = hs4[(size_t)csr_src[p0 + idx] * H + hh];
        float e = (qv.x + qv.y) + (qv.z + qv.w) + hdv;
        e = e > 0.f ? e : 0.2f * e;
        lalpha[idx * H + hh] = e;
        mm = fmaxf(mm, e);
      }
#pragma unroll
      for (int msk = 16; msk; msk >>= 1) mm = fmaxf(mm, __shfl_xor(mm, msk));
      float dd = 0.f;
      for (int idx = j; idx < deg; idx += 32) {
        float v = __expf(lalpha[idx * H + hh] - mm);
        lalpha[idx * H + hh] = v;
        dd += v;
      }
#pragma unroll
      for (int msk = 16; msk; msk >>= 1) dd += __shfl_xor(dd, msk);
      float inv = 1.f / (dd + 1e-16f);
      for (int idx = j; idx < deg; idx += 32)
        lalpha[idx * H + hh] *= inv;
    }
    __syncthreads();

    int p = 0;
    for (; p + 4 <= deg; p += 4) {  // unroll x4
      int s0 = lsrc[p], s1 = lsrc[p + 1], s2 = lsrc[p + 2], s3 = lsrc[p + 3];
      float a0 = lalpha[p * H + head];
      float a1 = lalpha[(p + 1) * H + head];
      float a2 = lalpha[(p + 2) * H + head];
      float a3 = lalpha[(p + 3) * H + head];
      const u16* h0 = h + (size_t)s0 * HC + c0;
      const u16* h1 = h + (size_t)s1 * HC + c0;
      const u16* h2 = h + (size_t)s2 * HC + c0;
      const u16* h3 = h + (size_t)s3 * HC + c0;
      if constexpr (VPT == 8) {
        u16x8 v0 = *(const u16x8*)h0, v1 = *(const u16x8*)h1;
        u16x8 v2 = *(const u16x8*)h2, v3 = *(const u16x8*)h3;
#pragma unroll
        for (int v = 0; v < 8; v++)
          acc[v] += (a0 * b2f(v0[v]) + a1 * b2f(v1[v])) + (a2 * b2f(v2[v]) + a3 * b2f(v3[v]));
      } else if constexpr (VPT == 4) {
        u16x4 v0 = *(const u16x4*)h0, v1 = *(const u16x4*)h1;
        u16x4 v2 = *(const u16x4*)h2, v3 = *(const u16x4*)h3;
#pragma unroll
        for (int v = 0; v < 4; v++)
          acc[v] += (a0 * b2f(v0[v]) + a1 * b2f(v1[v])) + (a2 * b2f(v2[v]) + a3 * b2f(v3[v]));
      } else {
        acc[0] += (a0 * b2f(h0[0]) + a1 * b2f(h1[0])) + (a2 * b2f(h2[0]) + a3 * b2f(h3[0]));
      }
    }
    for (; p < deg; ++p) {
      int s0 = lsrc[p];
      float a0 = lalpha[p * H + head];
      const u16* h0 = h + (size_t)s0 * HC + c0;
      if constexpr (VPT == 8) {
        u16x8 v0 = *(const u16x8*)h0;
#pragma unroll
        for (int v = 0; v < 8; v++) acc[v] += a0 * b2f(v0[v]);
      } else if constexpr (VPT == 4) {
        u16x4 v0 = *(const u16x4*)h0;
#pragma unroll
        for (int v = 0; v < 4; v++) acc[v] += a0 * b2f(v0[v]);
      } else {
        acc[0] += a0 * b2f(h0[0]);
      }
    }
  } else {
    // ---------------- fallback: chunked, 3 global passes
    if (crew) {
      float hdv = hd_s[hh];
      float mm = -1e30f;
      for (int p = p0 + j; p < p1; p += 32) {
        float4 qv = hs4[(size_t)csr_src[p] * H + hh];
        float e = (qv.x + qv.y) + (qv.z + qv.w) + hdv;
        e = e > 0.f ? e : 0.2f * e;
        mm = fmaxf(mm, e);
      }
#pragma unroll
      for (int msk = 16; msk; msk >>= 1) mm = fmaxf(mm, __shfl_xor(mm, msk));
      float dd = 0.f;
      for (int p = p0 + j; p < p1; p += 32) {
        float4 qv = hs4[(size_t)csr_src[p] * H + hh];
        float e = (qv.x + qv.y) + (qv.z + qv.w) + hdv;
        e = e > 0.f ? e : 0.2f * e;
        dd += __expf(e - mm);
      }
#pragma unroll
      for (int msk = 16; msk; msk >>= 1) dd += __shfl_xor(dd, msk);
      if (j == 0) { m_s[hh] = mm; inv_s[hh] = 1.f / (dd + 1e-16f); }
    }
    for (int base = p0; base < p1; base += CH) {
      int cend = base + CH < p1 ? base + CH : p1;
      __syncthreads();
      if (crew) {
        float hdv = hd_s[hh];
        float mmv = m_s[hh], inv = inv_s[hh];
        for (int p = base + j; p < cend; p += 32) {
          float4 qv = hs4[(size_t)csr_src[p] * H + hh];
          float e = (qv.x + qv.y) + (qv.z + qv.w) + hdv;
          e = e > 0.f ? e : 0.2f * e;
          lalpha[(p - base) * H + hh] = __expf(e - mmv) * inv;
        }
      }
      if (t < cend - base) lsrc[t] = csr_src[base + t];
      __syncthreads();
      for (int p = base; p < cend; ++p) {
        int s0 = lsrc[p - base];
        float a0 = lalpha[(p - base) * H + head];
        const u16* h0 = h + (size_t)s0 * HC + c0;
        if constexpr (VPT == 8) {
          u16x8 v0 = *(const u16x8*)h0;
#pragma unroll
          for (int v = 0; v < 8; v++) acc[v] += a0 * b2f(v0[v]);
        } else if constexpr (VPT == 4) {
          u16x4 v0 = *(const u16x4*)h0;
#pragma unroll
          for (int v = 0; v < 4; v++) acc[v] += a0 * b2f(v0[v]);
        } else {
          acc[0] += a0 * b2f(h0[0]);
        }
      }
    }
  }

  float r[VPT];
#pragma unroll
  for (int v = 0; v < VPT; v++) {
    r[v] = acc[v] + ldf(bias, c0 + v, isbf);
    if (do_elu) r[v] = r[v] > 0.f ? r[v] : expm1f(r[v]);
  }
  if (outb) {
    if constexpr (VPT == 8) {
      u16x8 o;
#pragma unroll
      for (int v = 0; v < 8; v++) o[v] = f2b(r[v]);
      *(u16x8*)(outb + (size_t)i * HC + c0) = o;
    } else if constexpr (VPT == 4) {
      u16x4 o;
#pragma unroll
      for (int v = 0; v < 4; v++) o[v] = f2b(r[v]);
      *(u16x4*)(outb + (size_t)i * HC + c0) = o;
    } else {
      outb[(size_t)i * HC + c0] = f2b(r[0]);
    }
  }
  if (outv) {
#pragma unroll
    for (int v = 0; v < VPT; v++)
      stf(outv, (size_t)10000 + (size_t)i * HC + c0 + v, isbf, r[v]);
  }
}

// ---------------------------------------------------------------- scores finish
__global__ void scores_kernel(const float* __restrict__ sc, const void* __restrict__ r3b,
                              void* __restrict__ scores, const int* __restrict__ FLAG) {
  int isbf = *FLAG;
  int i = blockIdx.x * 256 + threadIdx.x;
  if (i >= NN) return;
  float4 q = ((const float4*)sc)[i];
  stf(scores, i, isbf, (q.x + q.y) + (q.z + q.w) + ldf(r3b, 0, isbf));
}

// ---------------------------------------------------------------- launch
extern "C" void kernel_launch(void* const* d_in, const int* in_sizes, int n_in,
                              void* d_out, int out_size, void* d_ws, size_t ws_size,
                              hipStream_t stream) {
  const void* x   = d_in[0];
  const int* ei   = (const int*)d_in[1];
  const void* W1  = d_in[2];
  const void* as1 = d_in[3];
  const void* ad1 = d_in[4];
  const void* b1  = d_in[5];
  const void* W2  = d_in[6];
  const void* as2 = d_in[7];
  const void* ad2 = d_in[8];
  const void* b2  = d_in[9];
  const void* W3  = d_in[10];
  const void* as3 = d_in[11];
  const void* ad3 = d_in[12];
  const void* b3  = d_in[13];
  const void* r1w = d_in[14];
  const void* r1b = d_in[15];
  const void* r2w = d_in[16];
  const void* r2b = d_in[17];
  const void* r3w = d_in[18];
  const void* r3b = d_in[19];

  char* ws = (char*)d_ws;
  size_t o = 0;
  auto alloc = [&](size_t bytes) { void* p = ws + o; o += (bytes + 255) & ~(size_t)255; return p; };
  u16* XC     = (u16*)alloc((size_t)NN * 768 * 2);
  u16* W1T    = (u16*)alloc((size_t)2048 * 768 * 2);
  u16* W2T    = (u16*)alloc((size_t)1024 * 2048 * 2);
  u16* W3T    = (u16*)alloc((size_t)64 * 1024 * 2);
  u16* R1T    = (u16*)alloc((size_t)256 * 64 * 2);
  u16* R2T    = (u16*)alloc((size_t)128 * 256 * 2);
  u16* Hbuf   = (u16*)alloc((size_t)NN * 2048 * 2);
  u16* Xbuf   = (u16*)alloc((size_t)NN * 2048 * 2);
  u16* X3B    = (u16*)alloc((size_t)NN * 64 * 2);
  u16* H1B    = (u16*)alloc((size_t)NN * 256 * 2);
  // partial-sum layout: [node][head][4] floats per array
  float* HZ   = (float*)alloc((size_t)NN * 112 * 4);
  float* HS1  = HZ;                        // NN*8*4
  float* HD1  = HZ + (size_t)NN * 32;      // NN*8*4
  float* HS2  = HZ + (size_t)NN * 64;      // NN*4*4
  float* HD2  = HZ + (size_t)NN * 80;      // NN*4*4
  float* HS3  = HZ + (size_t)NN * 96;      // NN*1*4
  float* HD3  = HZ + (size_t)NN * 100;     // NN*1*4
  float* SC   = HZ + (size_t)NN * 104;     // NN*4 score partials
  float* SD   = HZ + (size_t)NN * 108;     // NN*4 dummy
  int* DEG    = (int*)alloc((size_t)NN * 4);
  int* OFFS   = (int*)alloc((size_t)(NN + 1) * 4);
  int* CURSOR = (int*)alloc((size_t)NN * 4);
  int* CSR    = (int*)alloc((size_t)NTOT * 4);
  int* FLAG   = (int*)alloc(256);

  detect_kernel<<<1, 64, 0, stream>>>(x, FLAG);
  cvt_kernel<<<(NN * 768 + 255) / 256, 256, 0, stream>>>(x, XC, NN * 768, FLAG);

  // batched weight transposes
  TD5 td;
  td.d[0] = {W1,  W1T, 768, 2048, 0};
  td.d[1] = {W2,  W2T, 2048, 1024, 0};
  td.d[2] = {W3,  W3T, 1024, 64, 0};
  td.d[3] = {r1w, R1T, 64, 256, 0};
  td.d[4] = {r2w, R2T, 256, 128, 0};
  int cum = 0;
  for (int k = 0; k < 5; k++) {
    td.d[k].t0 = cum;
    cum += (td.d[k].R / 32) * (td.d[k].C / 32);
  }
  transpose_all<<<cum, dim3(32, 8), 0, stream>>>(td, FLAG);

  init_kernel<<<(NN * 112 + 255) / 256, 256, 0, stream>>>(DEG, HZ, NN * 112);
  count_deg_kernel<<<(NE + 255) / 256, 256, 0, stream>>>(ei, DEG);
  scan_kernel<<<1, 1024, 0, stream>>>(DEG, OFFS, CURSOR, NN);
  scatter_kernel<<<(NTOT + 255) / 256, 256, 0, stream>>>(ei, CURSOR, CSR);

  const int MT = (NN + 127) / 128;   // 79
  const int MT64 = (NN + 63) / 64;   // 157

  // ---- layer 1: 768 -> 8 x 256 (fused hs/hd wave-partial dots; 64x128 tile)
  gemm_kernel<64, 128, 2, 2><<<MT64 * 16, 256, 0, stream>>>(
      XC, W1T, Hbuf, NN, 768, 2048, 16, nullptr, 0, as1, ad1, HS1, HD1, 8, 256, FLAG);
  agg_fused_kernel<2048, 8, 256, 8, 512><<<NN, 256, 0, stream>>>(
      Hbuf, HS1, HD1, CSR, OFFS, b1, Xbuf, nullptr, 1, FLAG);

  // ---- layer 2: 2048 -> 4 x 256
  gemm_kernel<64, 128, 2, 2><<<MT64 * 8, 256, 0, stream>>>(
      Xbuf, W2T, Hbuf, NN, 2048, 1024, 8, nullptr, 0, as2, ad2, HS2, HD2, 4, 256, FLAG);
  agg_fused_kernel<1024, 4, 256, 4, 512><<<NN, 256, 0, stream>>>(
      Hbuf, HS2, HD2, CSR, OFFS, b2, Xbuf, nullptr, 1, FLAG);

  // ---- layer 3: 1024 -> 1 x 64 (WTN=64=Cc -> single partial slot 0)
  gemm_kernel<128, 64, 4, 1><<<MT, 256, 0, stream>>>(
      Xbuf, W3T, Hbuf, NN, 1024, 64, 1, nullptr, 0, as3, ad3, HS3, HD3, 1, 64, FLAG);
  agg_fused_kernel<64, 1, 64, 1, 512><<<NN, 64, 0, stream>>>(
      Hbuf, HS3, HD3, CSR, OFFS, b3, X3B, d_out, 0, FLAG);

  // ---- reasoning MLP as MFMA GEMMs; final dot fused into 2nd GEMM epilogue
  gemm_kernel<64, 64, 2, 2><<<MT64 * 4, 256, 0, stream>>>(
      X3B, R1T, H1B, NN, 64, 256, 4, r1b, 1, nullptr, nullptr, nullptr, nullptr, 0, 0, FLAG);
  gemm_kernel<64, 64, 2, 2><<<MT64 * 2, 256, 0, stream>>>(
      H1B, R2T, nullptr, NN, 256, 128, 2, r2b, 1, r3w, r3w, SC, SD, 1, 128, FLAG);
  scores_kernel<<<(NN + 255) / 256, 256, 0, stream>>>(SC, r3b, d_out, FLAG);
}